// Round 13
// baseline (196.656 us; speedup 1.0000x reference)
//
#include <hip/hip_runtime.h>
#include <math.h>

#define BS 8
#define NQ 8192
#define NT 512
#define NTHR 512
#define CHUNKS 16            // NQ / NTHR columns per thread (SAP scan)
#define NW (NTHR / 64)       // 8 waves
#define MAXL (NT + 2)
#define QCAP 4608            // auction queue capacity (shorts)
#define KMASK 0xFFFFFFFFFFFFE000ull
#define WKB 248              // worker blocks (cand then C-fill); 8+248 = 256 CUs

#define DINF (__builtin_inf())

typedef float vf4 __attribute__((ext_vector_type(4)));

// f32 cost, FMA-contraction-free, bit-identical everywhere it is computed.
__device__ __forceinline__ float cost_f32(float qx, float qy, float cl, float tx, float ty) {
    float dx = __fsub_rn(qx, tx);
    float dy = __fsub_rn(qy, ty);
    float d2 = __fadd_rn(__fmul_rn(dx, dx), __fmul_rn(dy, dy));
    float d  = __fsqrt_rn(d2);
    return __fadd_rn(__fmul_rn(0.5f, d), cl);
}

__device__ __forceinline__ float cls_f32(float x) {
    float s;
    if (x >= 0.0f) { float e = expf(-x); s = 1.0f / (1.0f + e); }
    else           { float e = expf(x);  s = e / (1.0f + e); }
    return __fsub_rn(1.0f, s);
}

// packed (value,idx) key: non-negative doubles compare as u64 bits;
// low 13 bits hold column idx -> min == (min value, lowest idx).
__device__ __forceinline__ unsigned long long pack_key(double v, int idx) {
    double c = fmax(v, 0.0);
    return (((unsigned long long)__double_as_longlong(c)) & KMASK)
         | (unsigned long long)((unsigned)idx & 0x1FFFu);
}
__device__ __forceinline__ double key_val(unsigned long long k) {
    return __longlong_as_double((long long)(k & KMASK));
}

// Single mega-kernel, grid = BS + WKB = 256 blocks (1 block/CU, all resident).
// Blocks [0,BS): exact LSA solver (spin-wait on cand counters -> greedy ->
//   8-way-round auction -> register-v SAP, 1 barrier/iter).
// Blocks [BS,256): workers: cand slices (top-2/lane candidates + bound,
//   LDS-staged batch data), release-signal per-batch counter, then
//   grid-stride nontemporal C fill. cls recomputed bit-identically inline.
__global__ __launch_bounds__(NTHR, 1) void mega_kernel(
    const float* __restrict__ logits,
    const float* __restrict__ pred_points,
    const float* __restrict__ tgt_points,
    float* __restrict__ u0, int* __restrict__ jm, float* __restrict__ bnd,
    float* __restrict__ ccost, unsigned short* __restrict__ cidx,
    unsigned int* __restrict__ ctr,
    float* __restrict__ C,
    float* __restrict__ out_rows,
    float* __restrict__ out_cols) {
    const int tid = threadIdx.x;
    extern __shared__ char smem[];

    // ================= worker branch =================
    if (blockIdx.x >= BS) {
        const int wid = blockIdx.x - BS;             // 0..WKB-1
        float2* pd = (float2*)smem;                  // 64 KB
        float*  cl = (float*)(pd + NQ);              // 32 KB
        const int w = tid >> 6, lane = tid & 63;

        // ---- cand phase: group-blocks of 8 rows (one row per wave)
        for (int gb = wid; gb < 512; gb += WKB) {
            const int b = gb >> 6;
            __syncthreads();                         // LDS reuse guard
            const float4* p4 = (const float4*)(pred_points + (size_t)b * NQ * 2);
            for (int t = tid; t < NQ / 2; t += NTHR) ((float4*)pd)[t] = p4[t];
            for (int t = tid; t < NQ; t += NTHR) cl[t] = cls_f32(logits[b * NQ + t]);
            __syncthreads();

            const int g = gb * 8 + w;                // 0..4095
            const int i = g & (NT - 1);
            const float tx = tgt_points[(b * NT + i) * 2 + 0];
            const float ty = tgt_points[(b * NT + i) * 2 + 1];

            float a0 = DINF, a1 = DINF, am = DINF; int ai0 = 0, ai1 = 0;
            float b0 = DINF, b1 = DINF, bm = DINF; int bi0 = 0, bi1 = 0;
            for (int k = 0; k < NQ / 128; ++k) {     // 64 iters, 2 cols each
                const int c = k * 128 + 2 * lane;
                const float4 qq  = ((const float4*)pd)[c >> 1];
                const float2 cc2 = ((const float2*)cl)[c >> 1];
                const float cva = cost_f32(qq.x, qq.y, cc2.x, tx, ty);
                const float cvb = cost_f32(qq.z, qq.w, cc2.y, tx, ty);
                if (cva < a1) { am = a1; if (cva < a0) { a1 = a0; ai1 = ai0; a0 = cva; ai0 = c; } else { a1 = cva; ai1 = c; } }
                else am = fminf(am, cva);
                if (cvb < b1) { bm = b1; if (cvb < b0) { b1 = b0; bi1 = bi0; b0 = cvb; bi0 = c + 1; } else { b1 = cvb; bi1 = c + 1; } }
                else bm = fminf(bm, cvb);
            }
            float t0v, t1v, s3v; int t0i, t1i;
            const bool bWins = (b0 < a0) || (b0 == a0 && bi0 < ai0);
            if (!bWins) {
                t0v = a0; t0i = ai0;
                const bool a1W = (a1 < b0) || (a1 == b0 && ai1 < bi0);
                if (a1W) { t1v = a1; t1i = ai1; s3v = b0; }
                else     { t1v = b0; t1i = bi0; s3v = fminf(a1, b1); }
            } else {
                t0v = b0; t0i = bi0;
                const bool b1W = (b1 < a0) || (b1 == a0 && bi1 < ai0);
                if (b1W) { t1v = b1; t1i = bi1; s3v = a0; }
                else     { t1v = a0; t1i = ai0; s3v = fminf(b1, a1); }
            }
            const float bb0 = fminf(fminf(am, bm), s3v);

            ((float2*)(ccost + ((size_t)g << 7)))[lane] = make_float2(t0v, t1v);
            ((ushort2*)(cidx + ((size_t)g << 7)))[lane] =
                make_ushort2((unsigned short)t0i, (unsigned short)t1i);
            float bv = t0v; int bc = t0i; float bb = bb0;
            for (int off = 32; off > 0; off >>= 1) {
                float ov = __shfl_down(bv, off, 64);
                int   oc = __shfl_down(bc, off, 64);
                float ob = __shfl_down(bb, off, 64);
                if (ov < bv || (ov == bv && oc < bc)) { bv = ov; bc = oc; }
                bb = fminf(bb, ob);
            }
            if (lane == 0) { u0[g] = bv; jm[g] = bc; bnd[g] = bb; }

            __threadfence();                         // per-thread release flush
            __syncthreads();
            if (tid == 0) atomicAdd(&ctr[b], 8u);    // device-scope signal
        }

        // ---- C-fill phase (grid-stride, nontemporal stores, inline cls)
        const int g32 = tid & 31;
        for (int grp = wid; grp < BS * NQ / 16; grp += WKB) {
            const int bq = (grp << 4) + (tid >> 5);  // 16 queries per group
            const int b  = bq >> 13;
            const float2 q = ((const float2*)pred_points)[bq];
            const float clv = cls_f32(logits[bq]);
            const float* tb = tgt_points + b * NT * 2;
#pragma unroll
            for (int s = 0; s < 4; ++s) {
                const int t = g32 * 4 + s * 128;
                float4 A  = *(const float4*)(tb + t * 2);
                float4 Bv = *(const float4*)(tb + t * 2 + 4);
                vf4 r;
                r.x = cost_f32(q.x, q.y, clv, A.x,  A.y);
                r.y = cost_f32(q.x, q.y, clv, A.z,  A.w);
                r.z = cost_f32(q.x, q.y, clv, Bv.x, Bv.y);
                r.w = cost_f32(q.x, q.y, clv, Bv.z, Bv.w);
                __builtin_nontemporal_store(r, (vf4*)(C + (size_t)bq * NT + t));
            }
        }
        return;
    }

    // ================= solver branch =================
    const int b = blockIdx.x;
    double* v_s       = (double*)smem;                       // 8192
    double* u_s       = v_s + NQ;                            // 512
    double* l_minv    = u_s + NT;                            // MAXL
    double* l_v       = l_minv + MAXL;                       // MAXL
    double* bid_m2    = l_v + MAXL;                          // 8
    unsigned long long* p_k = (unsigned long long*)(bid_m2 + 8);  // 2*NW
    float*  tg        = (float*)(p_k + 2 * NW);              // 1024
    float*  bnd_s     = tg + NT * 2;                         // 512
    float*  bid_c     = bnd_s + NT;                          // 8
    int*    s_int     = (int*)(bid_c + 8);                   // 4
    int*    bid_j     = s_int + 4;                           // 8
    short*  bid_row   = (short*)(bid_j + 8);                 // 8
    short*  path_s    = bid_row + 8;                         // 8192
    short*  row4col_s = path_s + NQ;                         // 8192
    short*  col4row_s = row4col_s + NQ;                      // 512
    short*  jm_s      = col4row_s + NT;                      // 512
    short*  dflag     = jm_s + NT;                           // 512
    short*  sap_s     = dflag + NT;                          // 512
    short*  l_k       = sap_s + NT;                          // MAXL
    short*  l_r       = l_k + MAXL;                          // MAXL
    short*  queue_s   = l_r + MAXL;                          // QCAP

    // ---- pre-spin init (independent of cand outputs)
    for (int c = tid; c < NQ; c += NTHR) { row4col_s[c] = -1; v_s[c] = 0.0; }
    for (int r = tid; r < NT; r += NTHR) col4row_s[r] = -1;
    for (int t = tid; t < NT * 2; t += NTHR) tg[t] = tgt_points[b * NT * 2 + t];

    float  qx[CHUNKS], qy[CHUNKS], cl[CHUNKS];
    double vv[CHUNKS], sh[CHUNKS];
#pragma unroll
    for (int j = 0; j < CHUNKS; ++j) {
        int c = j * NTHR + tid;
        qx[j] = pred_points[(b * NQ + c) * 2 + 0];
        qy[j] = pred_points[(b * NQ + c) * 2 + 1];
        cl[j] = cls_f32(logits[b * NQ + c]);
    }

    // ---- spin-wait for this batch's cand results (workers always retire)
    if (tid == 0) {
        while (__hip_atomic_load(&ctr[b], __ATOMIC_ACQUIRE,
                                 __HIP_MEMORY_SCOPE_AGENT) < (unsigned)NT) { }
    }
    __syncthreads();
    __threadfence();   // acquire: invalidate stale cache lines before data reads

    for (int r = tid; r < NT; r += NTHR) {
        u_s[r]   = (double)u0[b * NT + r];
        jm_s[r]  = (short)jm[b * NT + r];
        bnd_s[r] = bnd[b * NT + r];
    }
    __syncthreads();

    // ---- parallel greedy: row r gets jm[r] iff no earlier row claims it
    {
        const int r = tid;
        const short jmr = jm_s[r];
        int conflict = 0;
        for (int r2 = 0; r2 < r; ++r2) conflict |= (jm_s[r2] == jmr) ? 1 : 0;
        dflag[r] = (short)conflict;
        if (!conflict) { col4row_s[r] = jmr; row4col_s[jmr] = (short)r; }
        __syncthreads();
        int rank = 0;
        for (int r2 = 0; r2 < r; ++r2) rank += dflag[r2];
        if (conflict) queue_s[rank] = (short)r;
        if (r == NT - 1) s_int[0] = rank + conflict;   // tail0
        __syncthreads();
    }

    // ---- parallel-round auction (R11-proven): up to 8 queue rows bid per
    // round; dup-losers requeue at tail (natural cluster interleave).
    int head = 0, tail = s_int[0], nsap = 0;
    {
        const int tail0 = tail;
        const int rcap = (tail0 + 64 < 256) ? tail0 + 64 : 256;
        const int w = tid >> 6, lane = tid & 63;
        int rounds = 0;
        while (head < tail && rounds < rcap) {
            const int nrows = (tail - head < NW) ? (tail - head) : NW;
            if (w < nrows) {
                const int row = queue_s[head + w];
                const int g = (b << 9) + row;
                const float2  cc = ((const float2*)(ccost + ((size_t)g << 7)))[lane];
                const ushort2 ci = ((const ushort2*)(cidx + ((size_t)g << 7)))[lane];
                const double rr0 = (double)cc.x - v_s[ci.x];
                const double rr1 = (double)cc.y - v_s[ci.y];
                const unsigned long long q0 = pack_key(rr0, ci.x);
                const unsigned long long q1 = pack_key(rr1, ci.y);
                unsigned long long k1  = q0 < q1 ? q0 : q1;
                unsigned long long m2b = (q0 < q1 ? q1 : q0) & KMASK;
                for (int m = 32; m > 0; m >>= 1) {
                    unsigned long long ok1 = __shfl_xor(k1, m, 64);
                    unsigned long long om2 = __shfl_xor(m2b, m, 64);
                    unsigned long long lo  = (ok1 < k1) ? ok1 : k1;
                    unsigned long long hiv = ((ok1 < k1) ? k1 : ok1) & KMASK;
                    k1 = lo;
                    if (om2 < m2b) m2b = om2;
                    if (hiv < m2b) m2b = hiv;
                }
                const double m2d = key_val(m2b);
                if (q0 == k1) bid_c[w] = cc.x;     // unique winner entry
                if (q1 == k1) bid_c[w] = cc.y;
                if (lane == 0) {
                    bid_row[w] = (short)row;
                    bid_m2[w]  = m2d;
                    bid_j[w]   = (m2d < (double)bnd_s[row]) ? (int)(k1 & 0x1FFFull) : -1;
                }
            }
            __syncthreads();                               // B1
            if (tid == 0) {
                int cj[NW]; int nc = 0;
                int t2 = tail, ns = nsap;
                for (int e = 0; e < nrows; ++e) {
                    const int j1 = bid_j[e];
                    const int row = bid_row[e];
                    if (j1 < 0) { sap_s[ns++] = (short)row; continue; }
                    int dup = 0;
                    for (int x = 0; x < nc; ++x) dup |= (cj[x] == j1);
                    if (dup) { queue_s[t2++] = (short)row; continue; }   // loser
                    cj[nc++] = j1;
                    const double m2d = bid_m2[e];
                    const int ko = row4col_s[j1];
                    row4col_s[j1]  = (short)row;
                    col4row_s[row] = (short)j1;
                    u_s[row] = m2d;
                    const double nv = (double)bid_c[e] - m2d;
                    if (nv < v_s[j1]) v_s[j1] = nv;
                    if (ko >= 0) { col4row_s[ko] = -1; queue_s[t2++] = (short)ko; }
                }
                s_int[0] = head + nrows; s_int[1] = t2; s_int[2] = ns;
            }
            __syncthreads();                               // B2
            head = s_int[0]; tail = s_int[1]; nsap = s_int[2];
            ++rounds;
        }
    }

    // refresh per-thread register v from LDS (auction's final v_s)
#pragma unroll
    for (int j = 0; j < CHUNKS; ++j) vv[j] = v_s[j * NTHR + tid];

    // ---- SAP for leftovers: exact full scan, v in REGISTERS, 1 barrier/iter
    const int NL = nsap + (tail - head);
    for (int di = 0; di < NL; ++di) {
        const int cur_row = (di < nsap) ? sap_s[di] : queue_s[head + di - nsap];
#pragma unroll
        for (int j = 0; j < CHUNKS; ++j) sh[j] = DINF;
        int    i    = cur_row;
        double minv = 0.0;
        int    len  = 0;
        int    sink = -1;

        for (;;) {
            const double w  = minv - u_s[i];
            const float  tx = tg[i * 2 + 0];
            const float  ty = tg[i * 2 + 1];

            double best = DINF;
            int bestc = NQ;
#pragma unroll
            for (int j = 0; j < CHUNKS; ++j) {
                const int c = j * NTHR + tid;
                float  cf = cost_f32(qx[j], qy[j], cl[j], tx, ty);
                double rr = (w + (double)cf) - vv[j];
                if (rr < sh[j]) { sh[j] = rr; path_s[c] = (short)i; }
                if (sh[j] < best) { best = sh[j]; bestc = c; }
            }
            unsigned long long bkey = pack_key(best, bestc);
            for (int off = 32; off > 0; off >>= 1) {
                unsigned long long ok = __shfl_down(bkey, off, 64);
                if (ok < bkey) bkey = ok;
            }
            const int par = len & 1;
            if ((tid & 63) == 0) p_k[par * NW + (tid >> 6)] = bkey;
            __syncthreads();                   // the ONE barrier per iteration
            bkey = p_k[par * NW + (tid & (NW - 1))];
            for (int m = NW >> 1; m > 0; m >>= 1) {
                unsigned long long ok = __shfl_xor(bkey, m, 64);
                if (ok < bkey) bkey = ok;
            }
            minv = key_val(bkey);
            const int k  = (int)(bkey & 0x1FFFull);
            const int rk = row4col_s[k];       // stable during Dijkstra
            if ((k & (NTHR - 1)) == tid) {     // owner: save+neutralize column
                const int jj = k >> 9;
#pragma unroll
                for (int j = 0; j < CHUNKS; ++j)
                    if (j == jj) { l_v[len] = vv[j]; vv[j] = -DINF; sh[j] = DINF; }
            }
            if (tid == 0) { l_k[len] = (short)k; l_minv[len] = minv; l_r[len] = (short)rk; }
            ++len;
            if (rk < 0) { sink = k; break; }
            i = rk;
        }
        __syncthreads();   // l_* / path_s writes visible

        const int L = len;
        for (int e = tid; e < L; e += NTHR) {
            const int rk2 = l_r[e];
            if (rk2 >= 0) u_s[rk2] += minv - l_minv[e];
        }
        if (tid == 0) u_s[cur_row] += minv;
        for (int e = 0; e < L; ++e) {          // owner restores its register v
            const int k2 = l_k[e];
            if ((k2 & (NTHR - 1)) == tid) {
                const int jj = k2 >> 9;
                const double nv = l_v[e] - (minv - l_minv[e]);
#pragma unroll
                for (int j = 0; j < CHUNKS; ++j)
                    if (j == jj) vv[j] = nv;
            }
        }
        if (tid == 0) {   // augment along the alternating path
            int j = sink;
            for (;;) {
                const int ii = path_s[j];
                row4col_s[j] = (short)ii;
                const int t = col4row_s[ii];
                col4row_s[ii] = (short)j;
                j = t;
                if (ii == cur_row) break;
            }
        }
        __syncthreads();
    }

    // row_ind = sorted(col4row), col_ind = argsort(col4row); values distinct
    for (int r = tid; r < NT; r += NTHR) {
        const int q = col4row_s[r];
        int rank = 0;
        for (int r2 = 0; r2 < NT; ++r2) rank += (col4row_s[r2] < q) ? 1 : 0;
        out_rows[b * NT + rank] = (float)q;
        out_cols[b * NT + rank] = (float)r;
    }
}

extern "C" void kernel_launch(void* const* d_in, const int* in_sizes, int n_in,
                              void* d_out, int out_size, void* d_ws, size_t ws_size,
                              hipStream_t stream) {
    const float* logits = (const float*)d_in[0];  // (8, 8192, 1)
    const float* pred   = (const float*)d_in[1];  // (8, 8192, 2)
    const float* tgt    = (const float*)d_in[2];  // (8, 512, 2)

    float* out  = (float*)d_out;
    float* C    = out;                                   // BS*NQ*NT
    float* orow = out + (size_t)BS * NQ * NT;            // BS*NT
    float* ocol = orow + (size_t)BS * NT;                // BS*NT

    char*  ws    = (char*)d_ws;
    float* u0    = (float*)ws;                                  // 16 KB
    float* bndp  = (float*)(ws + 16384);                        // 16 KB
    int*   jmn   = (int*)(ws + 32768);                          // 16 KB
    unsigned int* ctr = (unsigned int*)(ws + 49152);            // 32 B
    float* ccost = (float*)(ws + 65536);                        // 2 MB
    unsigned short* cidx = (unsigned short*)(ws + 65536 + 2097152); // 1 MB

    const size_t smem = 132480;

    hipMemsetAsync(ctr, 0, BS * sizeof(unsigned int), stream);
    mega_kernel<<<BS + WKB, NTHR, smem, stream>>>(
        logits, pred, tgt, u0, jmn, bndp, ccost, cidx, ctr, C, orow, ocol);
}

// Round 15
// 99.151 us; speedup vs baseline: 1.9834x; 1.9834x over previous
//
#include <hip/hip_runtime.h>
#include <math.h>

#define BS 8
#define NQ 8192
#define NT 512
#define NTHR 512
#define CHUNKS 16            // NQ / NTHR columns per thread (SAP scan)
#define NW (NTHR / 64)       // 8 waves
#define NG 16                // auction groups (32 lanes each)
#define MAXL (NT + 2)
#define QCAP 4608            // auction queue capacity (shorts)
#define KMASK 0xFFFFFFFFFFFFE000ull
#define CFB 240              // persistent C-fill blocks

#define DINF (__builtin_inf())

typedef float vf4 __attribute__((ext_vector_type(4)));

// f32 cost, FMA-contraction-free, bit-identical everywhere it is computed.
__device__ __forceinline__ float cost_f32(float qx, float qy, float cl, float tx, float ty) {
    float dx = __fsub_rn(qx, tx);
    float dy = __fsub_rn(qy, ty);
    float d2 = __fadd_rn(__fmul_rn(dx, dx), __fmul_rn(dy, dy));
    float d  = __fsqrt_rn(d2);
    return __fadd_rn(__fmul_rn(0.5f, d), cl);
}

__device__ __forceinline__ float cls_f32(float x) {
    float s;
    if (x >= 0.0f) { float e = expf(-x); s = 1.0f / (1.0f + e); }
    else           { float e = expf(x);  s = e / (1.0f + e); }
    return __fsub_rn(1.0f, s);
}

// packed (value,idx) key: non-negative doubles compare as u64 bits;
// low 13 bits hold column idx -> min == (min value, lowest idx).
__device__ __forceinline__ unsigned long long pack_key(double v, int idx) {
    double c = fmax(v, 0.0);
    return (((unsigned long long)__double_as_longlong(c)) & KMASK)
         | (unsigned long long)((unsigned)idx & 0x1FFFu);
}
__device__ __forceinline__ double key_val(unsigned long long k) {
    return __longlong_as_double((long long)(k & KMASK));
}

// 512 threads = 8 row-waves per block; batch data (pred + computed cls)
// staged once in 96KB LDS, 8x reuse. One block per batch writes cls out.
// Per lane: even/odd top-2 chains (2x ILP), merged with lowest-index
// tie-break. bnd = certified lower bound on every non-candidate column.
__global__ __launch_bounds__(512) void cand_kernel(
    const float* __restrict__ logits,
    const float* __restrict__ pred_points,
    const float* __restrict__ tgt_points,
    float* __restrict__ cls_out,
    float* __restrict__ u0, int* __restrict__ jm, float* __restrict__ bnd,
    float* __restrict__ ccost, unsigned short* __restrict__ cidx) {
    extern __shared__ char sm[];
    float2* pd = (float2*)sm;            // 8192 float2 = 64KB
    float*  cl = (float*)(pd + NQ);      // 8192 float  = 32KB

    const int tid = threadIdx.x;
    const int b   = blockIdx.x >> 6;     // 64 blocks per batch

    const float4* p4 = (const float4*)(pred_points + (size_t)b * NQ * 2);
    for (int t = tid; t < NQ / 2; t += 512) ((float4*)pd)[t] = p4[t];
    const bool wr = ((blockIdx.x & 63) == 0);
    for (int t = tid; t < NQ; t += 512) {
        const float c = cls_f32(logits[b * NQ + t]);
        cl[t] = c;
        if (wr) cls_out[b * NQ + t] = c;
    }
    __syncthreads();

    const int w = tid >> 6, lane = tid & 63;
    const int g = blockIdx.x * 8 + w;    // 0..4095
    const int i = g & (NT - 1);
    const float tx = tgt_points[(b * NT + i) * 2 + 0];
    const float ty = tgt_points[(b * NT + i) * 2 + 1];

    float a0 = DINF, a1 = DINF, am = DINF; int ai0 = 0, ai1 = 0;
    float b0 = DINF, b1 = DINF, bm = DINF; int bi0 = 0, bi1 = 0;
    for (int k = 0; k < NQ / 128; ++k) {     // 64 iters, 2 cols each
        const int c = k * 128 + 2 * lane;
        const float4 qq  = ((const float4*)pd)[c >> 1];
        const float2 cc2 = ((const float2*)cl)[c >> 1];
        const float cva = cost_f32(qq.x, qq.y, cc2.x, tx, ty);
        const float cvb = cost_f32(qq.z, qq.w, cc2.y, tx, ty);
        if (cva < a1) { am = a1; if (cva < a0) { a1 = a0; ai1 = ai0; a0 = cva; ai0 = c; } else { a1 = cva; ai1 = c; } }
        else am = fminf(am, cva);
        if (cvb < b1) { bm = b1; if (cvb < b0) { b1 = b0; bi1 = bi0; b0 = cvb; bi0 = c + 1; } else { b1 = cvb; bi1 = c + 1; } }
        else bm = fminf(bm, cvb);
    }
    float t0v, t1v, s3v; int t0i, t1i;
    const bool bWins = (b0 < a0) || (b0 == a0 && bi0 < ai0);
    if (!bWins) {
        t0v = a0; t0i = ai0;
        const bool a1W = (a1 < b0) || (a1 == b0 && ai1 < bi0);
        if (a1W) { t1v = a1; t1i = ai1; s3v = b0; }
        else     { t1v = b0; t1i = bi0; s3v = fminf(a1, b1); }
    } else {
        t0v = b0; t0i = bi0;
        const bool b1W = (b1 < a0) || (b1 == a0 && bi1 < ai0);
        if (b1W) { t1v = b1; t1i = bi1; s3v = a0; }
        else     { t1v = a0; t1i = ai0; s3v = fminf(b1, a1); }
    }
    const float bb0 = fminf(fminf(am, bm), s3v);

    ((float2*)(ccost + ((size_t)g << 7)))[lane] = make_float2(t0v, t1v);
    ((ushort2*)(cidx + ((size_t)g << 7)))[lane] =
        make_ushort2((unsigned short)t0i, (unsigned short)t1i);
    float bv = t0v; int bc = t0i; float bb = bb0;
    for (int off = 32; off > 0; off >>= 1) {
        float ov = __shfl_down(bv, off, 64);
        int   oc = __shfl_down(bc, off, 64);
        float ob = __shfl_down(bb, off, 64);
        if (ov < bv || (ov == bv && oc < bc)) { bv = ov; bc = oc; }
        bb = fminf(bb, ob);
    }
    if (lane == 0) { u0[g] = bv; jm[g] = bc; bnd[g] = bb; }
}

// Fused: blocks [0,BS) = exact LSA (greedy -> 16-way-round auction with
// R7-phased redundant commit -> 1-barrier register-v SAP);
// blocks [BS,BS+CFB) = persistent grid-stride nontemporal C fill.
__global__ __launch_bounds__(NTHR, 1) void fused_kernel(
    const float* __restrict__ pred_points,
    const float* __restrict__ tgt_points,
    const float* __restrict__ cls,
    const float* __restrict__ u0,
    const int* __restrict__ jm,
    const float* __restrict__ bnd,
    const float* __restrict__ ccost,
    const unsigned short* __restrict__ cidx,
    float* __restrict__ C,
    float* __restrict__ out_rows,
    float* __restrict__ out_cols) {
    const int tid = threadIdx.x;

    // ---------------- persistent C-fill branch ----------------
    if (blockIdx.x >= BS) {
        const int cfid = blockIdx.x - BS;            // 0..CFB-1
        const int ngrp = BS * NQ / 16;               // 4096 groups of 16 queries
        const int g32  = tid & 31;
        for (int grp = cfid; grp < ngrp; grp += CFB) {
            const int bq = (grp << 4) + (tid >> 5);  // 16 queries per group
            const int b  = bq >> 13;
            const float2 q = ((const float2*)pred_points)[bq];
            const float clv = cls[bq];
            const float* tb = tgt_points + b * NT * 2;
#pragma unroll
            for (int s = 0; s < 4; ++s) {
                const int t = g32 * 4 + s * 128;
                float4 A  = *(const float4*)(tb + t * 2);
                float4 Bv = *(const float4*)(tb + t * 2 + 4);
                vf4 r;
                r.x = cost_f32(q.x, q.y, clv, A.x,  A.y);
                r.y = cost_f32(q.x, q.y, clv, A.z,  A.w);
                r.z = cost_f32(q.x, q.y, clv, Bv.x, Bv.y);
                r.w = cost_f32(q.x, q.y, clv, Bv.z, Bv.w);
                __builtin_nontemporal_store(r, (vf4*)(C + (size_t)bq * NT + t));
            }
        }
        return;
    }

    // ---------------- LSA branch ----------------
    const int b = blockIdx.x;
    extern __shared__ char smem[];
    double* v_s       = (double*)smem;                       // NQ
    double* u_s       = v_s + NQ;                            // NT
    double* l_minv    = u_s + NT;                            // MAXL
    double* l_v       = l_minv + MAXL;                       // MAXL
    double* a_m2      = l_v + MAXL;                          // NG
    unsigned long long* p_k = (unsigned long long*)(a_m2 + NG);  // 2*NW
    float*  tg        = (float*)(p_k + 2 * NW);              // NT*2
    float*  bnd_s     = tg + NT * 2;                         // NT
    float*  a_c       = bnd_s + NT;                          // NG
    int*    s_int     = (int*)(a_c + NG);                    // 4
    int*    a_j       = s_int + 4;                           // NG
    short*  path_s    = (short*)(a_j + NG);                  // NQ
    short*  row4col_s = path_s + NQ;                         // NQ
    short*  col4row_s = row4col_s + NQ;                      // NT
    short*  jm_s      = col4row_s + NT;                      // NT
    short*  dflag     = jm_s + NT;                           // NT
    short*  sap_s     = dflag + NT;                          // NT
    short*  l_k       = sap_s + NT;                          // MAXL
    short*  l_r       = l_k + MAXL;                          // MAXL
    short*  queue_s   = l_r + MAXL;                          // QCAP

    for (int c = tid; c < NQ; c += NTHR) { row4col_s[c] = -1; v_s[c] = 0.0; }
    for (int r = tid; r < NT; r += NTHR) {
        col4row_s[r] = -1;
        u_s[r]   = (double)u0[b * NT + r];
        jm_s[r]  = (short)jm[b * NT + r];
        bnd_s[r] = bnd[b * NT + r];
    }
    for (int t = tid; t < NT * 2; t += NTHR) tg[t] = tgt_points[b * NT * 2 + t];

    // per-thread column state for SAP (registers)
    float  qx[CHUNKS], qy[CHUNKS], cl[CHUNKS];
    double vv[CHUNKS], sh[CHUNKS];
#pragma unroll
    for (int j = 0; j < CHUNKS; ++j) {
        int c = j * NTHR + tid;
        qx[j] = pred_points[(b * NQ + c) * 2 + 0];
        qy[j] = pred_points[(b * NQ + c) * 2 + 1];
        cl[j] = cls[b * NQ + c];
    }
    __syncthreads();

    // ---- parallel greedy: row r gets jm[r] iff no earlier row claims it
    {
        const int r = tid;
        const short jmr = jm_s[r];
        int conflict = 0;
        for (int r2 = 0; r2 < r; ++r2) conflict |= (jm_s[r2] == jmr) ? 1 : 0;
        dflag[r] = (short)conflict;
        if (!conflict) { col4row_s[r] = jmr; row4col_s[jmr] = (short)r; }
        __syncthreads();
        int rank = 0;
        for (int r2 = 0; r2 < r; ++r2) rank += dflag[r2];
        if (conflict) queue_s[rank] = (short)r;
        if (r == NT - 1) s_int[0] = rank + conflict;   // tail0
        __syncthreads();
    }

    // ---- 16-way-round auction (one row per 32-lane group). R7-phased:
    // bid -> B1 -> redundant READ-ONLY commit planning (identical across
    // threads; reads pre-round state, visible via B1) -> B2 -> WRITE-ONLY
    // commit (distinct addresses or identical values). Dup-losers requeue
    // at tail (R11 ordering). Cert-fail / round-cap -> exact SAP finisher.
    int head = 0, tail = s_int[0], nsap = 0;
    {
        const int tail0 = tail;
        int rcap = tail0 + 48; if (rcap > 192) rcap = 192;
        const int grp = tid >> 5, gl = tid & 31;
        int rounds = 0;
        while (head < tail && rounds < rcap) {
            const int nrows = (tail - head < NG) ? (tail - head) : NG;
            if (grp < nrows) {
                const int row = queue_s[head + grp];
                const int g = (b << 9) + row;
                const float4  cc = ((const float4*)(ccost + ((size_t)g << 7)))[gl];
                const ushort4 ci = ((const ushort4*)(cidx + ((size_t)g << 7)))[gl];
                const unsigned long long q0 = pack_key((double)cc.x - v_s[ci.x], ci.x);
                const unsigned long long q1 = pack_key((double)cc.y - v_s[ci.y], ci.y);
                const unsigned long long q2 = pack_key((double)cc.z - v_s[ci.z], ci.z);
                const unsigned long long q3 = pack_key((double)cc.w - v_s[ci.w], ci.w);
                unsigned long long ka = q0 < q1 ? q0 : q1, kb = q0 < q1 ? q1 : q0;
                unsigned long long kc = q2 < q3 ? q2 : q3, kd = q2 < q3 ? q3 : q2;
                unsigned long long k1  = ka < kc ? ka : kc;
                unsigned long long t2_ = ka < kc ? kc : ka;
                unsigned long long t3_ = kb < kd ? kb : kd;
                unsigned long long m2b = (t2_ < t3_ ? t2_ : t3_) & KMASK;
                for (int m = 16; m > 0; m >>= 1) {      // 32-lane group reduce
                    unsigned long long ok1 = __shfl_xor(k1, m, 32);
                    unsigned long long om2 = __shfl_xor(m2b, m, 32);
                    unsigned long long lo  = (ok1 < k1) ? ok1 : k1;
                    unsigned long long hiv = ((ok1 < k1) ? k1 : ok1) & KMASK;
                    k1 = lo;
                    if (om2 < m2b) m2b = om2;
                    if (hiv < m2b) m2b = hiv;
                }
                const double m2d = key_val(m2b);
                if (q0 == k1) a_c[grp] = cc.x;          // unique winner lane
                if (q1 == k1) a_c[grp] = cc.y;
                if (q2 == k1) a_c[grp] = cc.z;
                if (q3 == k1) a_c[grp] = cc.w;
                if (gl == 0) {
                    a_m2[grp] = m2d;
                    a_j[grp]  = (m2d < (double)bnd_s[row]) ? (int)(k1 & 0x1FFFull) : -1;
                }
            }
            __syncthreads();                             // B1
            // redundant planning (READS ONLY; identical on every thread)
            int   cjv[NG], kov[NG], rowv[NG], act[NG];   // act:0=skip 1=commit 2=dup 3=sap
            double m2v[NG]; float cwv[NG];
#pragma unroll
            for (int e = 0; e < NG; ++e) {
                cjv[e] = -1; act[e] = 0;
                if (e < nrows) {
                    rowv[e] = queue_s[head + e];
                    const int j1 = a_j[e];
                    if (j1 < 0) { act[e] = 3; }
                    else {
                        int dup = 0;
#pragma unroll
                        for (int x = 0; x < NG; ++x)
                            if (x < e) dup |= (cjv[x] == j1) ? 1 : 0;
                        if (dup) { act[e] = 2; }
                        else {
                            act[e] = 1; cjv[e] = j1;
                            kov[e] = row4col_s[j1];
                            m2v[e] = a_m2[e]; cwv[e] = a_c[e];
                        }
                    }
                }
            }
            __syncthreads();                             // B2
            // redundant commit (WRITES ONLY; distinct addrs or same value)
            {
                int t2 = tail, ns = nsap;
#pragma unroll
                for (int e = 0; e < NG; ++e) {
                    if (act[e] == 1) {
                        const int j1 = cjv[e];
                        row4col_s[j1]     = (short)rowv[e];
                        col4row_s[rowv[e]] = (short)j1;
                        u_s[rowv[e]] = m2v[e];
                        const double nv = (double)cwv[e] - m2v[e];
                        if (nv < v_s[j1]) v_s[j1] = nv;   // same-value RMW: benign
                        if (kov[e] >= 0) {
                            col4row_s[kov[e]] = -1;
                            queue_s[t2++] = (short)kov[e];
                        }
                    } else if (act[e] == 2) {
                        queue_s[t2++] = (short)rowv[e];
                    } else if (act[e] == 3) {
                        sap_s[ns++] = (short)rowv[e];
                    }
                }
                head += nrows; tail = t2; nsap = ns;
            }
            ++rounds;
        }
        // round-cap leftovers -> SAP list (redundant, identical)
        for (int e = head; e < tail; ++e) sap_s[nsap++] = queue_s[e];
    }
    __syncthreads();

    // refresh per-thread register v from LDS
#pragma unroll
    for (int j = 0; j < CHUNKS; ++j) vv[j] = v_s[j * NTHR + tid];

    // ---- SAP for leftovers: exact full scan, v in REGISTERS, 1 barrier/iter
    const int NL = nsap;
    for (int di = 0; di < NL; ++di) {
        const int cur_row = sap_s[di];
#pragma unroll
        for (int j = 0; j < CHUNKS; ++j) sh[j] = DINF;
        int    i    = cur_row;
        double minv = 0.0;
        int    len  = 0;
        int    sink = -1;

        for (;;) {
            const double w  = minv - u_s[i];
            const float  tx = tg[i * 2 + 0];
            const float  ty = tg[i * 2 + 1];

            double best = DINF;
            int bestc = NQ;
#pragma unroll
            for (int j = 0; j < CHUNKS; ++j) {
                const int c = j * NTHR + tid;
                float  cf = cost_f32(qx[j], qy[j], cl[j], tx, ty);
                double rr = (w + (double)cf) - vv[j];
                if (rr < sh[j]) { sh[j] = rr; path_s[c] = (short)i; }
                if (sh[j] < best) { best = sh[j]; bestc = c; }
            }
            unsigned long long bkey = pack_key(best, bestc);
            for (int off = 32; off > 0; off >>= 1) {
                unsigned long long ok = __shfl_down(bkey, off, 64);
                if (ok < bkey) bkey = ok;
            }
            const int par = len & 1;
            if ((tid & 63) == 0) p_k[par * NW + (tid >> 6)] = bkey;
            __syncthreads();                   // the ONE barrier per iteration
            bkey = p_k[par * NW + (tid & (NW - 1))];
            for (int m = NW >> 1; m > 0; m >>= 1) {
                unsigned long long ok = __shfl_xor(bkey, m, 64);
                if (ok < bkey) bkey = ok;
            }
            minv = key_val(bkey);
            const int k  = (int)(bkey & 0x1FFFull);
            const int rk = row4col_s[k];       // stable during Dijkstra
            if ((k & (NTHR - 1)) == tid) {     // owner: save+neutralize column
                const int jj = k >> 9;
#pragma unroll
                for (int j = 0; j < CHUNKS; ++j)
                    if (j == jj) { l_v[len] = vv[j]; vv[j] = -DINF; sh[j] = DINF; }
            }
            if (tid == 0) { l_k[len] = (short)k; l_minv[len] = minv; l_r[len] = (short)rk; }
            ++len;
            if (rk < 0) { sink = k; break; }
            i = rk;
        }
        __syncthreads();   // l_* / path_s writes visible

        const int L = len;
        for (int e = tid; e < L; e += NTHR) {
            const int rk2 = l_r[e];
            if (rk2 >= 0) u_s[rk2] += minv - l_minv[e];
        }
        if (tid == 0) u_s[cur_row] += minv;
        for (int e = 0; e < L; ++e) {          // owner restores its register v
            const int k2 = l_k[e];
            if ((k2 & (NTHR - 1)) == tid) {
                const int jj = k2 >> 9;
                const double nv = l_v[e] - (minv - l_minv[e]);
#pragma unroll
                for (int j = 0; j < CHUNKS; ++j)
                    if (j == jj) vv[j] = nv;
            }
        }
        if (tid == 0) {   // augment along the alternating path
            int j = sink;
            for (;;) {
                const int ii = path_s[j];
                row4col_s[j] = (short)ii;
                const int t = col4row_s[ii];
                col4row_s[ii] = (short)j;
                j = t;
                if (ii == cur_row) break;
            }
        }
        __syncthreads();
    }

    // row_ind = sorted(col4row), col_ind = argsort(col4row); values distinct
    for (int r = tid; r < NT; r += NTHR) {
        const int q = col4row_s[r];
        int rank = 0;
        for (int r2 = 0; r2 < NT; ++r2) rank += (col4row_s[r2] < q) ? 1 : 0;
        out_rows[b * NT + rank] = (float)q;
        out_cols[b * NT + rank] = (float)r;
    }
}

extern "C" void kernel_launch(void* const* d_in, const int* in_sizes, int n_in,
                              void* d_out, int out_size, void* d_ws, size_t ws_size,
                              hipStream_t stream) {
    const float* logits = (const float*)d_in[0];  // (8, 8192, 1)
    const float* pred   = (const float*)d_in[1];  // (8, 8192, 2)
    const float* tgt    = (const float*)d_in[2];  // (8, 512, 2)

    float* out  = (float*)d_out;
    float* C    = out;                                   // BS*NQ*NT
    float* orow = out + (size_t)BS * NQ * NT;            // BS*NT
    float* ocol = orow + (size_t)BS * NT;                // BS*NT

    char*  ws    = (char*)d_ws;
    float* cls   = (float*)ws;                                  // 256 KB
    float* u0    = (float*)(ws + 262144);                       // 16 KB
    float* bndp  = (float*)(ws + 278528);                       // 16 KB
    int*   jmn   = (int*)(ws + 294912);                         // 16 KB
    float* ccost = (float*)(ws + 311296);                       // 2 MB
    unsigned short* cidx = (unsigned short*)(ws + 311296 + 2097152); // 1 MB

    const size_t smem_cand  = 98304;    // 96 KB: pred(64K) + cls(32K)
    const size_t smem_fused = 132608;

    cand_kernel<<<BS * NT / 8, 512, smem_cand, stream>>>(
        logits, pred, tgt, cls, u0, jmn, bndp, ccost, cidx);
    fused_kernel<<<BS + CFB, NTHR, smem_fused, stream>>>(
        pred, tgt, cls, u0, jmn, bndp, ccost, cidx, C, orow, ocol);
}

// Round 16
// 88.547 us; speedup vs baseline: 2.2209x; 1.1197x over previous
//
#include <hip/hip_runtime.h>
#include <math.h>

#define BS 8
#define NQ 8192
#define NT 512
#define NTHR 512
#define CHUNKS 16            // NQ / NTHR columns per thread (SAP scan)
#define NW (NTHR / 64)       // 8 waves
#define NG 16                // auction groups (32 lanes each)
#define MAXL (NT + 2)
#define QCAP 4608            // auction queue capacity (shorts)
#define KMASK 0xFFFFFFFFFFFFE000ull
#define CFB 240              // persistent C-fill blocks

#define DINF (__builtin_inf())

typedef float vf4 __attribute__((ext_vector_type(4)));

// f32 cost, FMA-contraction-free, bit-identical everywhere it is computed.
__device__ __forceinline__ float cost_f32(float qx, float qy, float cl, float tx, float ty) {
    float dx = __fsub_rn(qx, tx);
    float dy = __fsub_rn(qy, ty);
    float d2 = __fadd_rn(__fmul_rn(dx, dx), __fmul_rn(dy, dy));
    float d  = __fsqrt_rn(d2);
    return __fadd_rn(__fmul_rn(0.5f, d), cl);
}

__device__ __forceinline__ float cls_f32(float x) {
    float s;
    if (x >= 0.0f) { float e = expf(-x); s = 1.0f / (1.0f + e); }
    else           { float e = expf(x);  s = e / (1.0f + e); }
    return __fsub_rn(1.0f, s);
}

// packed (value,idx) key: non-negative doubles compare as u64 bits;
// low 13 bits hold column idx -> min == (min value, lowest idx).
__device__ __forceinline__ unsigned long long pack_key(double v, int idx) {
    double c = fmax(v, 0.0);
    return (((unsigned long long)__double_as_longlong(c)) & KMASK)
         | (unsigned long long)((unsigned)idx & 0x1FFFu);
}
__device__ __forceinline__ double key_val(unsigned long long k) {
    return __longlong_as_double((long long)(k & KMASK));
}

// merge two (top2 + bound) chains with exact lowest-index tie-break.
// Inputs: (a0,a1,ai0,ai1,am) and (b0,b1,bi0,bi1,bm); am/bm = min of all
// chain values excluding the chain's own top-2. Output same structure.
__device__ __forceinline__ void merge2(
    float a0, float a1, int ai0, int ai1, float am,
    float b0, float b1, int bi0, int bi1, float bm,
    float& o0, float& o1, int& oi0, int& oi1, float& om) {
    float s3;
    const bool bWins = (b0 < a0) || (b0 == a0 && bi0 < ai0);
    if (!bWins) {
        o0 = a0; oi0 = ai0;
        const bool a1W = (a1 < b0) || (a1 == b0 && ai1 < bi0);
        if (a1W) { o1 = a1; oi1 = ai1; s3 = b0; }
        else     { o1 = b0; oi1 = bi0; s3 = fminf(a1, b1); }
    } else {
        o0 = b0; oi0 = bi0;
        const bool b1W = (b1 < a0) || (b1 == a0 && bi1 < ai0);
        if (b1W) { o1 = b1; oi1 = bi1; s3 = a0; }
        else     { o1 = a0; oi1 = ai0; s3 = fminf(b1, a1); }
    }
    om = fminf(fminf(am, bm), s3);
}

// 1024 threads = 16 row-waves per block; 256 blocks = one pass over the GPU.
// Batch data (pred + computed cls) staged once in 96KB LDS, 16x reuse.
// Per lane: FOUR independent top-2 chains (cols mod 4) -> 2-level merge.
// bnd = certified lower bound on every non-candidate column.
__global__ __launch_bounds__(1024) void cand_kernel(
    const float* __restrict__ logits,
    const float* __restrict__ pred_points,
    const float* __restrict__ tgt_points,
    float* __restrict__ cls_out,
    float* __restrict__ u0, int* __restrict__ jm, float* __restrict__ bnd,
    float* __restrict__ ccost, unsigned short* __restrict__ cidx) {
    extern __shared__ char sm[];
    float2* pd = (float2*)sm;            // 8192 float2 = 64KB
    float*  cl = (float*)(pd + NQ);      // 8192 float  = 32KB

    const int tid = threadIdx.x;
    const int b   = blockIdx.x >> 5;     // 32 blocks per batch

    const float4* p4 = (const float4*)(pred_points + (size_t)b * NQ * 2);
    for (int t = tid; t < NQ / 2; t += 1024) ((float4*)pd)[t] = p4[t];
    for (int t = tid; t < NQ; t += 1024) cl[t] = cls_f32(logits[b * NQ + t]);
    __syncthreads();
    if ((blockIdx.x & 31) == 0) {        // one block per batch exports cls
        for (int t = tid; t < NQ; t += 1024) cls_out[b * NQ + t] = cl[t];
    }

    const int w = tid >> 6, lane = tid & 63;
    const int i = (blockIdx.x & 31) * 16 + w;    // row in batch
    const int g = b * NT + i;                    // 0..4095
    const float tx = tgt_points[g * 2 + 0];
    const float ty = tgt_points[g * 2 + 1];

    // 4 independent chains: values DINF-init; am overwrite-on-evict is exact
    // because a1 is non-increasing (evicted a1 <= all previously folded).
    float A0 = DINF, A1 = DINF, Am = DINF; int Ai0 = 0, Ai1 = 0;
    float B0 = DINF, B1 = DINF, Bm = DINF; int Bi0 = 0, Bi1 = 0;
    float C0 = DINF, C1 = DINF, Cm = DINF; int Ci0 = 0, Ci1 = 0;
    float D0 = DINF, D1 = DINF, Dm = DINF; int Di0 = 0, Di1 = 0;
    for (int k = 0; k < NQ / 256; ++k) {     // 32 iters, 4 cols each
        const int c = k * 256 + 4 * lane;
        const float4 p01 = ((const float4*)pd)[(c >> 1) + 0];
        const float4 p23 = ((const float4*)pd)[(c >> 1) + 1];
        const float4 c4  = ((const float4*)cl)[c >> 2];
        const float v0 = cost_f32(p01.x, p01.y, c4.x, tx, ty);
        const float v1 = cost_f32(p01.z, p01.w, c4.y, tx, ty);
        const float v2 = cost_f32(p23.x, p23.y, c4.z, tx, ty);
        const float v3 = cost_f32(p23.z, p23.w, c4.w, tx, ty);
        if (v0 < A1) { Am = A1; if (v0 < A0) { A1 = A0; Ai1 = Ai0; A0 = v0; Ai0 = c; } else { A1 = v0; Ai1 = c; } }
        else Am = fminf(Am, v0);
        if (v1 < B1) { Bm = B1; if (v1 < B0) { B1 = B0; Bi1 = Bi0; B0 = v1; Bi0 = c + 1; } else { B1 = v1; Bi1 = c + 1; } }
        else Bm = fminf(Bm, v1);
        if (v2 < C1) { Cm = C1; if (v2 < C0) { C1 = C0; Ci1 = Ci0; C0 = v2; Ci0 = c + 2; } else { C1 = v2; Ci1 = c + 2; } }
        else Cm = fminf(Cm, v2);
        if (v3 < D1) { Dm = D1; if (v3 < D0) { D1 = D0; Di1 = Di0; D0 = v3; Di0 = c + 3; } else { D1 = v3; Di1 = c + 3; } }
        else Dm = fminf(Dm, v3);
    }
    // 2-level merge tree (R10-verified merge semantics)
    float ab0, ab1, abm; int abi0, abi1;
    float cd0, cd1, cdm; int cdi0, cdi1;
    float t0v, t1v, bb0; int t0i, t1i;
    merge2(A0, A1, Ai0, Ai1, Am, B0, B1, Bi0, Bi1, Bm, ab0, ab1, abi0, abi1, abm);
    merge2(C0, C1, Ci0, Ci1, Cm, D0, D1, Di0, Di1, Dm, cd0, cd1, cdi0, cdi1, cdm);
    merge2(ab0, ab1, abi0, abi1, abm, cd0, cd1, cdi0, cdi1, cdm, t0v, t1v, t0i, t1i, bb0);

    ((float2*)(ccost + ((size_t)g << 7)))[lane] = make_float2(t0v, t1v);
    ((ushort2*)(cidx + ((size_t)g << 7)))[lane] =
        make_ushort2((unsigned short)t0i, (unsigned short)t1i);
    float bv = t0v; int bc = t0i; float bb = bb0;
    for (int off = 32; off > 0; off >>= 1) {
        float ov = __shfl_down(bv, off, 64);
        int   oc = __shfl_down(bc, off, 64);
        float ob = __shfl_down(bb, off, 64);
        if (ov < bv || (ov == bv && oc < bc)) { bv = ov; bc = oc; }
        bb = fminf(bb, ob);
    }
    if (lane == 0) { u0[g] = bv; jm[g] = bc; bnd[g] = bb; }
}

// Fused: blocks [0,BS) = exact LSA (greedy -> 16-way-round auction with
// R7-phased redundant commit -> 1-barrier register-v SAP);
// blocks [BS,BS+CFB) = persistent grid-stride nontemporal C fill.
// (VERBATIM from R15 — passed at 99 us; do not touch.)
__global__ __launch_bounds__(NTHR, 1) void fused_kernel(
    const float* __restrict__ pred_points,
    const float* __restrict__ tgt_points,
    const float* __restrict__ cls,
    const float* __restrict__ u0,
    const int* __restrict__ jm,
    const float* __restrict__ bnd,
    const float* __restrict__ ccost,
    const unsigned short* __restrict__ cidx,
    float* __restrict__ C,
    float* __restrict__ out_rows,
    float* __restrict__ out_cols) {
    const int tid = threadIdx.x;

    // ---------------- persistent C-fill branch ----------------
    if (blockIdx.x >= BS) {
        const int cfid = blockIdx.x - BS;            // 0..CFB-1
        const int ngrp = BS * NQ / 16;               // 4096 groups of 16 queries
        const int g32  = tid & 31;
        for (int grp = cfid; grp < ngrp; grp += CFB) {
            const int bq = (grp << 4) + (tid >> 5);  // 16 queries per group
            const int b  = bq >> 13;
            const float2 q = ((const float2*)pred_points)[bq];
            const float clv = cls[bq];
            const float* tb = tgt_points + b * NT * 2;
#pragma unroll
            for (int s = 0; s < 4; ++s) {
                const int t = g32 * 4 + s * 128;
                float4 A  = *(const float4*)(tb + t * 2);
                float4 Bv = *(const float4*)(tb + t * 2 + 4);
                vf4 r;
                r.x = cost_f32(q.x, q.y, clv, A.x,  A.y);
                r.y = cost_f32(q.x, q.y, clv, A.z,  A.w);
                r.z = cost_f32(q.x, q.y, clv, Bv.x, Bv.y);
                r.w = cost_f32(q.x, q.y, clv, Bv.z, Bv.w);
                __builtin_nontemporal_store(r, (vf4*)(C + (size_t)bq * NT + t));
            }
        }
        return;
    }

    // ---------------- LSA branch ----------------
    const int b = blockIdx.x;
    extern __shared__ char smem[];
    double* v_s       = (double*)smem;                       // NQ
    double* u_s       = v_s + NQ;                            // NT
    double* l_minv    = u_s + NT;                            // MAXL
    double* l_v       = l_minv + MAXL;                       // MAXL
    double* a_m2      = l_v + MAXL;                          // NG
    unsigned long long* p_k = (unsigned long long*)(a_m2 + NG);  // 2*NW
    float*  tg        = (float*)(p_k + 2 * NW);              // NT*2
    float*  bnd_s     = tg + NT * 2;                         // NT
    float*  a_c       = bnd_s + NT;                          // NG
    int*    s_int     = (int*)(a_c + NG);                    // 4
    int*    a_j       = s_int + 4;                           // NG
    short*  path_s    = (short*)(a_j + NG);                  // NQ
    short*  row4col_s = path_s + NQ;                         // NQ
    short*  col4row_s = row4col_s + NQ;                      // NT
    short*  jm_s      = col4row_s + NT;                      // NT
    short*  dflag     = jm_s + NT;                           // NT
    short*  sap_s     = dflag + NT;                          // NT
    short*  l_k       = sap_s + NT;                          // MAXL
    short*  l_r       = l_k + MAXL;                          // MAXL
    short*  queue_s   = l_r + MAXL;                          // QCAP

    for (int c = tid; c < NQ; c += NTHR) { row4col_s[c] = -1; v_s[c] = 0.0; }
    for (int r = tid; r < NT; r += NTHR) {
        col4row_s[r] = -1;
        u_s[r]   = (double)u0[b * NT + r];
        jm_s[r]  = (short)jm[b * NT + r];
        bnd_s[r] = bnd[b * NT + r];
    }
    for (int t = tid; t < NT * 2; t += NTHR) tg[t] = tgt_points[b * NT * 2 + t];

    // per-thread column state for SAP (registers)
    float  qx[CHUNKS], qy[CHUNKS], cl[CHUNKS];
    double vv[CHUNKS], sh[CHUNKS];
#pragma unroll
    for (int j = 0; j < CHUNKS; ++j) {
        int c = j * NTHR + tid;
        qx[j] = pred_points[(b * NQ + c) * 2 + 0];
        qy[j] = pred_points[(b * NQ + c) * 2 + 1];
        cl[j] = cls[b * NQ + c];
    }
    __syncthreads();

    // ---- parallel greedy: row r gets jm[r] iff no earlier row claims it
    {
        const int r = tid;
        const short jmr = jm_s[r];
        int conflict = 0;
        for (int r2 = 0; r2 < r; ++r2) conflict |= (jm_s[r2] == jmr) ? 1 : 0;
        dflag[r] = (short)conflict;
        if (!conflict) { col4row_s[r] = jmr; row4col_s[jmr] = (short)r; }
        __syncthreads();
        int rank = 0;
        for (int r2 = 0; r2 < r; ++r2) rank += dflag[r2];
        if (conflict) queue_s[rank] = (short)r;
        if (r == NT - 1) s_int[0] = rank + conflict;   // tail0
        __syncthreads();
    }

    // ---- 16-way-round auction (one row per 32-lane group). R7-phased:
    // bid -> B1 -> redundant READ-ONLY commit planning -> B2 -> WRITE-ONLY
    // commit. Dup-losers requeue at tail. Cert-fail/round-cap -> SAP.
    int head = 0, tail = s_int[0], nsap = 0;
    {
        const int tail0 = tail;
        int rcap = tail0 + 48; if (rcap > 192) rcap = 192;
        const int grp = tid >> 5, gl = tid & 31;
        int rounds = 0;
        while (head < tail && rounds < rcap) {
            const int nrows = (tail - head < NG) ? (tail - head) : NG;
            if (grp < nrows) {
                const int row = queue_s[head + grp];
                const int g = (b << 9) + row;
                const float4  cc = ((const float4*)(ccost + ((size_t)g << 7)))[gl];
                const ushort4 ci = ((const ushort4*)(cidx + ((size_t)g << 7)))[gl];
                const unsigned long long q0 = pack_key((double)cc.x - v_s[ci.x], ci.x);
                const unsigned long long q1 = pack_key((double)cc.y - v_s[ci.y], ci.y);
                const unsigned long long q2 = pack_key((double)cc.z - v_s[ci.z], ci.z);
                const unsigned long long q3 = pack_key((double)cc.w - v_s[ci.w], ci.w);
                unsigned long long ka = q0 < q1 ? q0 : q1, kb = q0 < q1 ? q1 : q0;
                unsigned long long kc = q2 < q3 ? q2 : q3, kd = q2 < q3 ? q3 : q2;
                unsigned long long k1  = ka < kc ? ka : kc;
                unsigned long long t2_ = ka < kc ? kc : ka;
                unsigned long long t3_ = kb < kd ? kb : kd;
                unsigned long long m2b = (t2_ < t3_ ? t2_ : t3_) & KMASK;
                for (int m = 16; m > 0; m >>= 1) {      // 32-lane group reduce
                    unsigned long long ok1 = __shfl_xor(k1, m, 32);
                    unsigned long long om2 = __shfl_xor(m2b, m, 32);
                    unsigned long long lo  = (ok1 < k1) ? ok1 : k1;
                    unsigned long long hiv = ((ok1 < k1) ? k1 : ok1) & KMASK;
                    k1 = lo;
                    if (om2 < m2b) m2b = om2;
                    if (hiv < m2b) m2b = hiv;
                }
                const double m2d = key_val(m2b);
                if (q0 == k1) a_c[grp] = cc.x;          // unique winner lane
                if (q1 == k1) a_c[grp] = cc.y;
                if (q2 == k1) a_c[grp] = cc.z;
                if (q3 == k1) a_c[grp] = cc.w;
                if (gl == 0) {
                    a_m2[grp] = m2d;
                    a_j[grp]  = (m2d < (double)bnd_s[row]) ? (int)(k1 & 0x1FFFull) : -1;
                }
            }
            __syncthreads();                             // B1
            // redundant planning (READS ONLY; identical on every thread)
            int   cjv[NG], kov[NG], rowv[NG], act[NG];   // 0=skip 1=commit 2=dup 3=sap
            double m2v[NG]; float cwv[NG];
#pragma unroll
            for (int e = 0; e < NG; ++e) {
                cjv[e] = -1; act[e] = 0;
                if (e < nrows) {
                    rowv[e] = queue_s[head + e];
                    const int j1 = a_j[e];
                    if (j1 < 0) { act[e] = 3; }
                    else {
                        int dup = 0;
#pragma unroll
                        for (int x = 0; x < NG; ++x)
                            if (x < e) dup |= (cjv[x] == j1) ? 1 : 0;
                        if (dup) { act[e] = 2; }
                        else {
                            act[e] = 1; cjv[e] = j1;
                            kov[e] = row4col_s[j1];
                            m2v[e] = a_m2[e]; cwv[e] = a_c[e];
                        }
                    }
                }
            }
            __syncthreads();                             // B2
            // redundant commit (WRITES ONLY; distinct addrs or same value)
            {
                int t2 = tail, ns = nsap;
#pragma unroll
                for (int e = 0; e < NG; ++e) {
                    if (act[e] == 1) {
                        const int j1 = cjv[e];
                        row4col_s[j1]     = (short)rowv[e];
                        col4row_s[rowv[e]] = (short)j1;
                        u_s[rowv[e]] = m2v[e];
                        const double nv = (double)cwv[e] - m2v[e];
                        if (nv < v_s[j1]) v_s[j1] = nv;   // same-value RMW: benign
                        if (kov[e] >= 0) {
                            col4row_s[kov[e]] = -1;
                            queue_s[t2++] = (short)kov[e];
                        }
                    } else if (act[e] == 2) {
                        queue_s[t2++] = (short)rowv[e];
                    } else if (act[e] == 3) {
                        sap_s[ns++] = (short)rowv[e];
                    }
                }
                head += nrows; tail = t2; nsap = ns;
            }
            ++rounds;
        }
        // round-cap leftovers -> SAP list (redundant, identical)
        for (int e = head; e < tail; ++e) sap_s[nsap++] = queue_s[e];
    }
    __syncthreads();

    // refresh per-thread register v from LDS
#pragma unroll
    for (int j = 0; j < CHUNKS; ++j) vv[j] = v_s[j * NTHR + tid];

    // ---- SAP for leftovers: exact full scan, v in REGISTERS, 1 barrier/iter
    const int NL = nsap;
    for (int di = 0; di < NL; ++di) {
        const int cur_row = sap_s[di];
#pragma unroll
        for (int j = 0; j < CHUNKS; ++j) sh[j] = DINF;
        int    i    = cur_row;
        double minv = 0.0;
        int    len  = 0;
        int    sink = -1;

        for (;;) {
            const double w  = minv - u_s[i];
            const float  tx = tg[i * 2 + 0];
            const float  ty = tg[i * 2 + 1];

            double best = DINF;
            int bestc = NQ;
#pragma unroll
            for (int j = 0; j < CHUNKS; ++j) {
                const int c = j * NTHR + tid;
                float  cf = cost_f32(qx[j], qy[j], cl[j], tx, ty);
                double rr = (w + (double)cf) - vv[j];
                if (rr < sh[j]) { sh[j] = rr; path_s[c] = (short)i; }
                if (sh[j] < best) { best = sh[j]; bestc = c; }
            }
            unsigned long long bkey = pack_key(best, bestc);
            for (int off = 32; off > 0; off >>= 1) {
                unsigned long long ok = __shfl_down(bkey, off, 64);
                if (ok < bkey) bkey = ok;
            }
            const int par = len & 1;
            if ((tid & 63) == 0) p_k[par * NW + (tid >> 6)] = bkey;
            __syncthreads();                   // the ONE barrier per iteration
            bkey = p_k[par * NW + (tid & (NW - 1))];
            for (int m = NW >> 1; m > 0; m >>= 1) {
                unsigned long long ok = __shfl_xor(bkey, m, 64);
                if (ok < bkey) bkey = ok;
            }
            minv = key_val(bkey);
            const int k  = (int)(bkey & 0x1FFFull);
            const int rk = row4col_s[k];       // stable during Dijkstra
            if ((k & (NTHR - 1)) == tid) {     // owner: save+neutralize column
                const int jj = k >> 9;
#pragma unroll
                for (int j = 0; j < CHUNKS; ++j)
                    if (j == jj) { l_v[len] = vv[j]; vv[j] = -DINF; sh[j] = DINF; }
            }
            if (tid == 0) { l_k[len] = (short)k; l_minv[len] = minv; l_r[len] = (short)rk; }
            ++len;
            if (rk < 0) { sink = k; break; }
            i = rk;
        }
        __syncthreads();   // l_* / path_s writes visible

        const int L = len;
        for (int e = tid; e < L; e += NTHR) {
            const int rk2 = l_r[e];
            if (rk2 >= 0) u_s[rk2] += minv - l_minv[e];
        }
        if (tid == 0) u_s[cur_row] += minv;
        for (int e = 0; e < L; ++e) {          // owner restores its register v
            const int k2 = l_k[e];
            if ((k2 & (NTHR - 1)) == tid) {
                const int jj = k2 >> 9;
                const double nv = l_v[e] - (minv - l_minv[e]);
#pragma unroll
                for (int j = 0; j < CHUNKS; ++j)
                    if (j == jj) vv[j] = nv;
            }
        }
        if (tid == 0) {   // augment along the alternating path
            int j = sink;
            for (;;) {
                const int ii = path_s[j];
                row4col_s[j] = (short)ii;
                const int t = col4row_s[ii];
                col4row_s[ii] = (short)j;
                j = t;
                if (ii == cur_row) break;
            }
        }
        __syncthreads();
    }

    // row_ind = sorted(col4row), col_ind = argsort(col4row); values distinct
    for (int r = tid; r < NT; r += NTHR) {
        const int q = col4row_s[r];
        int rank = 0;
        for (int r2 = 0; r2 < NT; ++r2) rank += (col4row_s[r2] < q) ? 1 : 0;
        out_rows[b * NT + rank] = (float)q;
        out_cols[b * NT + rank] = (float)r;
    }
}

extern "C" void kernel_launch(void* const* d_in, const int* in_sizes, int n_in,
                              void* d_out, int out_size, void* d_ws, size_t ws_size,
                              hipStream_t stream) {
    const float* logits = (const float*)d_in[0];  // (8, 8192, 1)
    const float* pred   = (const float*)d_in[1];  // (8, 8192, 2)
    const float* tgt    = (const float*)d_in[2];  // (8, 512, 2)

    float* out  = (float*)d_out;
    float* C    = out;                                   // BS*NQ*NT
    float* orow = out + (size_t)BS * NQ * NT;            // BS*NT
    float* ocol = orow + (size_t)BS * NT;                // BS*NT

    char*  ws    = (char*)d_ws;
    float* cls   = (float*)ws;                                  // 256 KB
    float* u0    = (float*)(ws + 262144);                       // 16 KB
    float* bndp  = (float*)(ws + 278528);                       // 16 KB
    int*   jmn   = (int*)(ws + 294912);                         // 16 KB
    float* ccost = (float*)(ws + 311296);                       // 2 MB
    unsigned short* cidx = (unsigned short*)(ws + 311296 + 2097152); // 1 MB

    const size_t smem_cand  = 98304;    // 96 KB: pred(64K) + cls(32K)
    const size_t smem_fused = 132608;

    cand_kernel<<<BS * 32, 1024, smem_cand, stream>>>(
        logits, pred, tgt, cls, u0, jmn, bndp, ccost, cidx);
    fused_kernel<<<BS + CFB, NTHR, smem_fused, stream>>>(
        pred, tgt, cls, u0, jmn, bndp, ccost, cidx, C, orow, ocol);
}

// Round 17
// 80.863 us; speedup vs baseline: 2.4320x; 1.0950x over previous
//
#include <hip/hip_runtime.h>
#include <math.h>

#define BS 8
#define NQ 8192
#define NT 512
#define NTHR 512
#define CHUNKS 16            // NQ / NTHR columns per thread (SAP scan)
#define NW (NTHR / 64)       // 8 waves
#define NG 16                // auction groups (32 lanes each)
#define MAXL (NT + 2)
#define QCAP 4608            // auction queue capacity (shorts)
#define KMASK 0xFFFFFFFFFFFFE000ull
#define CFB 240              // persistent C-fill blocks

#define DINF (__builtin_inf())

typedef float vf4 __attribute__((ext_vector_type(4)));

// f32 cost, FMA-contraction-free, bit-identical everywhere it is computed.
__device__ __forceinline__ float cost_f32(float qx, float qy, float cl, float tx, float ty) {
    float dx = __fsub_rn(qx, tx);
    float dy = __fsub_rn(qy, ty);
    float d2 = __fadd_rn(__fmul_rn(dx, dx), __fmul_rn(dy, dy));
    float d  = __fsqrt_rn(d2);
    return __fadd_rn(__fmul_rn(0.5f, d), cl);
}

__device__ __forceinline__ float cls_f32(float x) {
    float s;
    if (x >= 0.0f) { float e = expf(-x); s = 1.0f / (1.0f + e); }
    else           { float e = expf(x);  s = e / (1.0f + e); }
    return __fsub_rn(1.0f, s);
}

// packed (value,idx) key: non-negative doubles compare as u64 bits;
// low 13 bits hold column idx -> min == (min value, lowest idx).
__device__ __forceinline__ unsigned long long pack_key(double v, int idx) {
    double c = fmax(v, 0.0);
    return (((unsigned long long)__double_as_longlong(c)) & KMASK)
         | (unsigned long long)((unsigned)idx & 0x1FFFu);
}
__device__ __forceinline__ double key_val(unsigned long long k) {
    return __longlong_as_double((long long)(k & KMASK));
}

// merge two (top2 + bound) chains with exact lowest-index tie-break.
__device__ __forceinline__ void merge2(
    float a0, float a1, int ai0, int ai1, float am,
    float b0, float b1, int bi0, int bi1, float bm,
    float& o0, float& o1, int& oi0, int& oi1, float& om) {
    float s3;
    const bool bWins = (b0 < a0) || (b0 == a0 && bi0 < ai0);
    if (!bWins) {
        o0 = a0; oi0 = ai0;
        const bool a1W = (a1 < b0) || (a1 == b0 && ai1 < bi0);
        if (a1W) { o1 = a1; oi1 = ai1; s3 = b0; }
        else     { o1 = b0; oi1 = bi0; s3 = fminf(a1, b1); }
    } else {
        o0 = b0; oi0 = bi0;
        const bool b1W = (b1 < a0) || (b1 == a0 && bi1 < ai0);
        if (b1W) { o1 = b1; oi1 = bi1; s3 = a0; }
        else     { o1 = a0; oi1 = ai0; s3 = fminf(b1, a1); }
    }
    om = fminf(fminf(am, bm), s3);
}

// 1024 threads = 16 row-waves per block; 256 blocks = one pass (R16-proven).
__global__ __launch_bounds__(1024) void cand_kernel(
    const float* __restrict__ logits,
    const float* __restrict__ pred_points,
    const float* __restrict__ tgt_points,
    float* __restrict__ cls_out,
    float* __restrict__ u0, int* __restrict__ jm, float* __restrict__ bnd,
    float* __restrict__ ccost, unsigned short* __restrict__ cidx) {
    extern __shared__ char sm[];
    float2* pd = (float2*)sm;            // 8192 float2 = 64KB
    float*  cl = (float*)(pd + NQ);      // 8192 float  = 32KB

    const int tid = threadIdx.x;
    const int b   = blockIdx.x >> 5;     // 32 blocks per batch

    const float4* p4 = (const float4*)(pred_points + (size_t)b * NQ * 2);
    for (int t = tid; t < NQ / 2; t += 1024) ((float4*)pd)[t] = p4[t];
    for (int t = tid; t < NQ; t += 1024) cl[t] = cls_f32(logits[b * NQ + t]);
    __syncthreads();
    if ((blockIdx.x & 31) == 0) {        // one block per batch exports cls
        for (int t = tid; t < NQ; t += 1024) cls_out[b * NQ + t] = cl[t];
    }

    const int w = tid >> 6, lane = tid & 63;
    const int i = (blockIdx.x & 31) * 16 + w;    // row in batch
    const int g = b * NT + i;                    // 0..4095
    const float tx = tgt_points[g * 2 + 0];
    const float ty = tgt_points[g * 2 + 1];

    float A0 = DINF, A1 = DINF, Am = DINF; int Ai0 = 0, Ai1 = 0;
    float B0 = DINF, B1 = DINF, Bm = DINF; int Bi0 = 0, Bi1 = 0;
    float C0 = DINF, C1 = DINF, Cm = DINF; int Ci0 = 0, Ci1 = 0;
    float D0 = DINF, D1 = DINF, Dm = DINF; int Di0 = 0, Di1 = 0;
    for (int k = 0; k < NQ / 256; ++k) {     // 32 iters, 4 cols each
        const int c = k * 256 + 4 * lane;
        const float4 p01 = ((const float4*)pd)[(c >> 1) + 0];
        const float4 p23 = ((const float4*)pd)[(c >> 1) + 1];
        const float4 c4  = ((const float4*)cl)[c >> 2];
        const float v0 = cost_f32(p01.x, p01.y, c4.x, tx, ty);
        const float v1 = cost_f32(p01.z, p01.w, c4.y, tx, ty);
        const float v2 = cost_f32(p23.x, p23.y, c4.z, tx, ty);
        const float v3 = cost_f32(p23.z, p23.w, c4.w, tx, ty);
        if (v0 < A1) { Am = A1; if (v0 < A0) { A1 = A0; Ai1 = Ai0; A0 = v0; Ai0 = c; } else { A1 = v0; Ai1 = c; } }
        else Am = fminf(Am, v0);
        if (v1 < B1) { Bm = B1; if (v1 < B0) { B1 = B0; Bi1 = Bi0; B0 = v1; Bi0 = c + 1; } else { B1 = v1; Bi1 = c + 1; } }
        else Bm = fminf(Bm, v1);
        if (v2 < C1) { Cm = C1; if (v2 < C0) { C1 = C0; Ci1 = Ci0; C0 = v2; Ci0 = c + 2; } else { C1 = v2; Ci1 = c + 2; } }
        else Cm = fminf(Cm, v2);
        if (v3 < D1) { Dm = D1; if (v3 < D0) { D1 = D0; Di1 = Di0; D0 = v3; Di0 = c + 3; } else { D1 = v3; Di1 = c + 3; } }
        else Dm = fminf(Dm, v3);
    }
    float ab0, ab1, abm; int abi0, abi1;
    float cd0, cd1, cdm; int cdi0, cdi1;
    float t0v, t1v, bb0; int t0i, t1i;
    merge2(A0, A1, Ai0, Ai1, Am, B0, B1, Bi0, Bi1, Bm, ab0, ab1, abi0, abi1, abm);
    merge2(C0, C1, Ci0, Ci1, Cm, D0, D1, Di0, Di1, Dm, cd0, cd1, cdi0, cdi1, cdm);
    merge2(ab0, ab1, abi0, abi1, abm, cd0, cd1, cdi0, cdi1, cdm, t0v, t1v, t0i, t1i, bb0);

    ((float2*)(ccost + ((size_t)g << 7)))[lane] = make_float2(t0v, t1v);
    ((ushort2*)(cidx + ((size_t)g << 7)))[lane] =
        make_ushort2((unsigned short)t0i, (unsigned short)t1i);
    float bv = t0v; int bc = t0i; float bb = bb0;
    for (int off = 32; off > 0; off >>= 1) {
        float ov = __shfl_down(bv, off, 64);
        int   oc = __shfl_down(bc, off, 64);
        float ob = __shfl_down(bb, off, 64);
        if (ov < bv || (ov == bv && oc < bc)) { bv = ov; bc = oc; }
        bb = fminf(bb, ob);
    }
    if (lane == 0) { u0[g] = bv; jm[g] = bc; bnd[g] = bb; }
}

// Fused: blocks [0,BS) = exact LSA (atomicMin greedy -> 16-way auction with
// candidate prefetch + R7-phased redundant commit -> 1-barrier register-v
// SAP); blocks [BS,BS+CFB) = persistent grid-stride nontemporal C fill.
__global__ __launch_bounds__(NTHR, 1) void fused_kernel(
    const float* __restrict__ pred_points,
    const float* __restrict__ tgt_points,
    const float* __restrict__ cls,
    const float* __restrict__ u0,
    const int* __restrict__ jm,
    const float* __restrict__ bnd,
    const float* __restrict__ ccost,
    const unsigned short* __restrict__ cidx,
    float* __restrict__ C,
    float* __restrict__ out_rows,
    float* __restrict__ out_cols) {
    const int tid = threadIdx.x;

    // ---------------- persistent C-fill branch ----------------
    if (blockIdx.x >= BS) {
        const int cfid = blockIdx.x - BS;            // 0..CFB-1
        const int ngrp = BS * NQ / 16;               // 4096 groups of 16 queries
        const int g32  = tid & 31;
        for (int grp = cfid; grp < ngrp; grp += CFB) {
            const int bq = (grp << 4) + (tid >> 5);  // 16 queries per group
            const int b  = bq >> 13;
            const float2 q = ((const float2*)pred_points)[bq];
            const float clv = cls[bq];
            const float* tb = tgt_points + b * NT * 2;
#pragma unroll
            for (int s = 0; s < 4; ++s) {
                const int t = g32 * 4 + s * 128;
                float4 A  = *(const float4*)(tb + t * 2);
                float4 Bv = *(const float4*)(tb + t * 2 + 4);
                vf4 r;
                r.x = cost_f32(q.x, q.y, clv, A.x,  A.y);
                r.y = cost_f32(q.x, q.y, clv, A.z,  A.w);
                r.z = cost_f32(q.x, q.y, clv, Bv.x, Bv.y);
                r.w = cost_f32(q.x, q.y, clv, Bv.z, Bv.w);
                __builtin_nontemporal_store(r, (vf4*)(C + (size_t)bq * NT + t));
            }
        }
        return;
    }

    // ---------------- LSA branch ----------------
    const int b = blockIdx.x;
    extern __shared__ char smem[];
    double* v_s       = (double*)smem;                       // NQ
    double* u_s       = v_s + NQ;                            // NT
    double* l_minv    = u_s + NT;                            // MAXL
    double* l_v       = l_minv + MAXL;                       // MAXL
    double* a_m2      = l_v + MAXL;                          // NG
    unsigned long long* p_k = (unsigned long long*)(a_m2 + NG);  // 2*NW
    float*  tg        = (float*)(p_k + 2 * NW);              // NT*2
    float*  bnd_s     = tg + NT * 2;                         // NT
    float*  a_c       = bnd_s + NT;                          // NG
    int*    s_int     = (int*)(a_c + NG);                    // 4
    int*    a_j       = s_int + 4;                           // NG
    int*    wcnt      = a_j + NG;                            // NW
    short*  path_s    = (short*)(wcnt + NW);                 // NQ
    short*  row4col_s = path_s + NQ;                         // NQ
    short*  col4row_s = row4col_s + NQ;                      // NT
    short*  jm_s      = col4row_s + NT;                      // NT
    short*  sap_s     = jm_s + NT;                           // NT
    short*  l_k       = sap_s + NT;                          // MAXL
    short*  l_r       = l_k + MAXL;                          // MAXL
    short*  queue_s   = l_r + MAXL;                          // QCAP

    // init (v_s deferred: its space doubles as greedy scratch)
    for (int c = tid; c < NQ; c += NTHR) row4col_s[c] = -1;
    for (int r = tid; r < NT; r += NTHR) {
        col4row_s[r] = -1;
        u_s[r]   = (double)u0[b * NT + r];
        jm_s[r]  = (short)jm[b * NT + r];
        bnd_s[r] = bnd[b * NT + r];
    }
    for (int t = tid; t < NT * 2; t += NTHR) tg[t] = tgt_points[b * NT * 2 + t];

    // per-thread column state for SAP (registers)
    float  qx[CHUNKS], qy[CHUNKS], cl[CHUNKS];
    double vv[CHUNKS], sh[CHUNKS];
#pragma unroll
    for (int j = 0; j < CHUNKS; ++j) {
        int c = j * NTHR + tid;
        qx[j] = pred_points[(b * NQ + c) * 2 + 0];
        qy[j] = pred_points[(b * NQ + c) * 2 + 1];
        cl[j] = cls[b * NQ + c];
    }
    __syncthreads();

    // ---- greedy via LDS atomicMin (winner = lowest row, == old rule) +
    // ballot-based compaction (queue order = ascending row, == old order).
    {
        int* scratch = (int*)v_s;          // v_s not yet initialized
        const int r = tid;                 // NT == NTHR
        const int jmr = jm_s[r];
        scratch[jmr] = 0x7FFFFFFF;         // same-addr same-val: benign
        __syncthreads();
        atomicMin(&scratch[jmr], r);
        __syncthreads();
        const bool conflict = (scratch[jmr] != r);
        if (!conflict) { col4row_s[r] = (short)jmr; row4col_s[jmr] = (short)r; }
        const unsigned long long bal = __ballot(conflict);
        const int lane = tid & 63, w = tid >> 6;
        if (lane == 0) wcnt[w] = __popcll(bal);
        __syncthreads();
        int pre = 0, tot = 0;
        for (int x = 0; x < NW; ++x) { if (x < w) pre += wcnt[x]; tot += wcnt[x]; }
        const int rank = pre + __popcll(bal & ((1ull << lane) - 1ull));
        if (conflict) queue_s[rank] = (short)r;
        if (tid == 0) s_int[0] = 0;        // placeholder
        // now init v_s (overwrites scratch) — all reads of scratch done
        __syncthreads();
        for (int c = tid; c < NQ; c += NTHR) v_s[c] = 0.0;
        if (tid == 0) s_int[0] = tot;      // tail0
        __syncthreads();
    }

    // ---- 16-way-round auction (one row per 32-lane group). R7-phased:
    // bid -> B1 -> redundant READ-ONLY planning -> B2 -> WRITE-ONLY commit.
    // Candidate loads for round r+1 are PREFETCHED during round r (positions
    // < tail-at-bid are >=2 barriers old; misses fall back to direct load).
    int head = 0, tail = s_int[0], nsap = 0;
    {
        const int tail0 = tail;
        int rcap = tail0 + 48; if (rcap > 192) rcap = 192;
        const int grp = tid >> 5, gl = tid & 31;
        int rounds = 0;
        int pf_row = -1; float4 pf_cc; ushort4 pf_ci;
        while (head < tail && rounds < rcap) {
            const int nrows = (tail - head < NG) ? (tail - head) : NG;
            if (grp < nrows) {
                const int row = queue_s[head + grp];
                float4 cc; ushort4 ci;
                if (row == pf_row) { cc = pf_cc; ci = pf_ci; }
                else {
                    const int g = (b << 9) + row;
                    cc = ((const float4*)(ccost + ((size_t)g << 7)))[gl];
                    ci = ((const ushort4*)(cidx + ((size_t)g << 7)))[gl];
                }
                const unsigned long long q0 = pack_key((double)cc.x - v_s[ci.x], ci.x);
                const unsigned long long q1 = pack_key((double)cc.y - v_s[ci.y], ci.y);
                const unsigned long long q2 = pack_key((double)cc.z - v_s[ci.z], ci.z);
                const unsigned long long q3 = pack_key((double)cc.w - v_s[ci.w], ci.w);
                unsigned long long ka = q0 < q1 ? q0 : q1, kb = q0 < q1 ? q1 : q0;
                unsigned long long kc = q2 < q3 ? q2 : q3, kd = q2 < q3 ? q3 : q2;
                unsigned long long k1  = ka < kc ? ka : kc;
                unsigned long long t2_ = ka < kc ? kc : ka;
                unsigned long long t3_ = kb < kd ? kb : kd;
                unsigned long long m2b = (t2_ < t3_ ? t2_ : t3_) & KMASK;
                for (int m = 16; m > 0; m >>= 1) {      // 32-lane group reduce
                    unsigned long long ok1 = __shfl_xor(k1, m, 32);
                    unsigned long long om2 = __shfl_xor(m2b, m, 32);
                    unsigned long long lo  = (ok1 < k1) ? ok1 : k1;
                    unsigned long long hiv = ((ok1 < k1) ? k1 : ok1) & KMASK;
                    k1 = lo;
                    if (om2 < m2b) m2b = om2;
                    if (hiv < m2b) m2b = hiv;
                }
                const double m2d = key_val(m2b);
                if (q0 == k1) a_c[grp] = cc.x;          // unique winner lane
                if (q1 == k1) a_c[grp] = cc.y;
                if (q2 == k1) a_c[grp] = cc.z;
                if (q3 == k1) a_c[grp] = cc.w;
                if (gl == 0) {
                    a_m2[grp] = m2d;
                    a_j[grp]  = (m2d < (double)bnd_s[row]) ? (int)(k1 & 0x1FFFull) : -1;
                }
            }
            // prefetch next round's candidate row (entries < tail are stable)
            {
                const int np = head + nrows + grp;
                if (np < tail) {
                    const int prow = queue_s[np];
                    const int pg = (b << 9) + prow;
                    pf_cc = ((const float4*)(ccost + ((size_t)pg << 7)))[gl];
                    pf_ci = ((const ushort4*)(cidx + ((size_t)pg << 7)))[gl];
                    pf_row = prow;
                } else pf_row = -1;
            }
            __syncthreads();                             // B1
            // redundant planning (READS ONLY; identical on every thread)
            int   cjv[NG], kov[NG], rowv[NG], act[NG];   // 0=skip 1=commit 2=dup 3=sap
            double m2v[NG]; float cwv[NG];
#pragma unroll
            for (int e = 0; e < NG; ++e) {
                cjv[e] = -1; act[e] = 0;
                if (e < nrows) {
                    rowv[e] = queue_s[head + e];
                    const int j1 = a_j[e];
                    if (j1 < 0) { act[e] = 3; }
                    else {
                        int dup = 0;
#pragma unroll
                        for (int x = 0; x < NG; ++x)
                            if (x < e) dup |= (cjv[x] == j1) ? 1 : 0;
                        if (dup) { act[e] = 2; }
                        else {
                            act[e] = 1; cjv[e] = j1;
                            kov[e] = row4col_s[j1];
                            m2v[e] = a_m2[e]; cwv[e] = a_c[e];
                        }
                    }
                }
            }
            __syncthreads();                             // B2
            // redundant commit (WRITES ONLY; distinct addrs or same value)
            {
                int t2 = tail, ns = nsap;
#pragma unroll
                for (int e = 0; e < NG; ++e) {
                    if (act[e] == 1) {
                        const int j1 = cjv[e];
                        row4col_s[j1]     = (short)rowv[e];
                        col4row_s[rowv[e]] = (short)j1;
                        u_s[rowv[e]] = m2v[e];
                        const double nv = (double)cwv[e] - m2v[e];
                        if (nv < v_s[j1]) v_s[j1] = nv;   // same-value RMW: benign
                        if (kov[e] >= 0) {
                            col4row_s[kov[e]] = -1;
                            queue_s[t2++] = (short)kov[e];
                        }
                    } else if (act[e] == 2) {
                        queue_s[t2++] = (short)rowv[e];
                    } else if (act[e] == 3) {
                        sap_s[ns++] = (short)rowv[e];
                    }
                }
                head += nrows; tail = t2; nsap = ns;
            }
            ++rounds;
        }
        // round-cap leftovers -> SAP list (redundant, identical)
        for (int e = head; e < tail; ++e) sap_s[nsap++] = queue_s[e];
    }
    __syncthreads();

    // refresh per-thread register v from LDS
#pragma unroll
    for (int j = 0; j < CHUNKS; ++j) vv[j] = v_s[j * NTHR + tid];

    // ---- SAP for leftovers: exact full scan, v in REGISTERS, 1 barrier/iter
    const int NL = nsap;
    for (int di = 0; di < NL; ++di) {
        const int cur_row = sap_s[di];
#pragma unroll
        for (int j = 0; j < CHUNKS; ++j) sh[j] = DINF;
        int    i    = cur_row;
        double minv = 0.0;
        int    len  = 0;
        int    sink = -1;

        for (;;) {
            const double w  = minv - u_s[i];
            const float  tx = tg[i * 2 + 0];
            const float  ty = tg[i * 2 + 1];

            double best = DINF;
            int bestc = NQ;
#pragma unroll
            for (int j = 0; j < CHUNKS; ++j) {
                const int c = j * NTHR + tid;
                float  cf = cost_f32(qx[j], qy[j], cl[j], tx, ty);
                double rr = (w + (double)cf) - vv[j];
                if (rr < sh[j]) { sh[j] = rr; path_s[c] = (short)i; }
                if (sh[j] < best) { best = sh[j]; bestc = c; }
            }
            unsigned long long bkey = pack_key(best, bestc);
            for (int off = 32; off > 0; off >>= 1) {
                unsigned long long ok = __shfl_down(bkey, off, 64);
                if (ok < bkey) bkey = ok;
            }
            const int par = len & 1;
            if ((tid & 63) == 0) p_k[par * NW + (tid >> 6)] = bkey;
            __syncthreads();                   // the ONE barrier per iteration
            bkey = p_k[par * NW + (tid & (NW - 1))];
            for (int m = NW >> 1; m > 0; m >>= 1) {
                unsigned long long ok = __shfl_xor(bkey, m, 64);
                if (ok < bkey) bkey = ok;
            }
            minv = key_val(bkey);
            const int k  = (int)(bkey & 0x1FFFull);
            const int rk = row4col_s[k];       // stable during Dijkstra
            if ((k & (NTHR - 1)) == tid) {     // owner: save+neutralize column
                const int jj = k >> 9;
#pragma unroll
                for (int j = 0; j < CHUNKS; ++j)
                    if (j == jj) { l_v[len] = vv[j]; vv[j] = -DINF; sh[j] = DINF; }
            }
            if (tid == 0) { l_k[len] = (short)k; l_minv[len] = minv; l_r[len] = (short)rk; }
            ++len;
            if (rk < 0) { sink = k; break; }
            i = rk;
        }
        __syncthreads();   // l_* / path_s writes visible

        const int L = len;
        for (int e = tid; e < L; e += NTHR) {
            const int rk2 = l_r[e];
            if (rk2 >= 0) u_s[rk2] += minv - l_minv[e];
        }
        if (tid == 0) u_s[cur_row] += minv;
        for (int e = 0; e < L; ++e) {          // owner restores its register v
            const int k2 = l_k[e];
            if ((k2 & (NTHR - 1)) == tid) {
                const int jj = k2 >> 9;
                const double nv = l_v[e] - (minv - l_minv[e]);
#pragma unroll
                for (int j = 0; j < CHUNKS; ++j)
                    if (j == jj) vv[j] = nv;
            }
        }
        if (tid == 0) {   // augment along the alternating path
            int j = sink;
            for (;;) {
                const int ii = path_s[j];
                row4col_s[j] = (short)ii;
                const int t = col4row_s[ii];
                col4row_s[ii] = (short)j;
                j = t;
                if (ii == cur_row) break;
            }
        }
        __syncthreads();
    }

    // row_ind = sorted(col4row), col_ind = argsort(col4row); values distinct
    for (int r = tid; r < NT; r += NTHR) {
        const int q = col4row_s[r];
        int rank = 0;
        for (int r2 = 0; r2 < NT; ++r2) rank += (col4row_s[r2] < q) ? 1 : 0;
        out_rows[b * NT + rank] = (float)q;
        out_cols[b * NT + rank] = (float)r;
    }
}

extern "C" void kernel_launch(void* const* d_in, const int* in_sizes, int n_in,
                              void* d_out, int out_size, void* d_ws, size_t ws_size,
                              hipStream_t stream) {
    const float* logits = (const float*)d_in[0];  // (8, 8192, 1)
    const float* pred   = (const float*)d_in[1];  // (8, 8192, 2)
    const float* tgt    = (const float*)d_in[2];  // (8, 512, 2)

    float* out  = (float*)d_out;
    float* C    = out;                                   // BS*NQ*NT
    float* orow = out + (size_t)BS * NQ * NT;            // BS*NT
    float* ocol = orow + (size_t)BS * NT;                // BS*NT

    char*  ws    = (char*)d_ws;
    float* cls   = (float*)ws;                                  // 256 KB
    float* u0    = (float*)(ws + 262144);                       // 16 KB
    float* bndp  = (float*)(ws + 278528);                       // 16 KB
    int*   jmn   = (int*)(ws + 294912);                         // 16 KB
    float* ccost = (float*)(ws + 311296);                       // 2 MB
    unsigned short* cidx = (unsigned short*)(ws + 311296 + 2097152); // 1 MB

    const size_t smem_cand  = 98304;    // 96 KB: pred(64K) + cls(32K)
    const size_t smem_fused = 132608;

    cand_kernel<<<BS * 32, 1024, smem_cand, stream>>>(
        logits, pred, tgt, cls, u0, jmn, bndp, ccost, cidx);
    fused_kernel<<<BS + CFB, NTHR, smem_fused, stream>>>(
        pred, tgt, cls, u0, jmn, bndp, ccost, cidx, C, orow, ocol);
}

// Round 18
// 72.994 us; speedup vs baseline: 2.6941x; 1.1078x over previous
//
#include <hip/hip_runtime.h>
#include <math.h>

#define BS 8
#define NQ 8192
#define NT 512
#define NTHR 512
#define CHUNKS 16            // NQ / NTHR columns per thread (SAP scan)
#define NW (NTHR / 64)       // 8 waves
#define MAXL (NT + 2)
#define KMASK 0xFFFFFFFFFFFFE000ull
#define CFB 240              // persistent C-fill blocks
#define SWCAP 96             // Jacobi sweep cap (SAP finishes leftovers)

#define DINF (__builtin_inf())

typedef float vf4 __attribute__((ext_vector_type(4)));

// f32 cost, FMA-contraction-free, bit-identical everywhere it is computed.
__device__ __forceinline__ float cost_f32(float qx, float qy, float cl, float tx, float ty) {
    float dx = __fsub_rn(qx, tx);
    float dy = __fsub_rn(qy, ty);
    float d2 = __fadd_rn(__fmul_rn(dx, dx), __fmul_rn(dy, dy));
    float d  = __fsqrt_rn(d2);
    return __fadd_rn(__fmul_rn(0.5f, d), cl);
}

__device__ __forceinline__ float cls_f32(float x) {
    float s;
    if (x >= 0.0f) { float e = expf(-x); s = 1.0f / (1.0f + e); }
    else           { float e = expf(x);  s = e / (1.0f + e); }
    return __fsub_rn(1.0f, s);
}

// packed (value,idx) key: non-negative doubles compare as u64 bits;
// low 13 bits hold idx -> min == (min value, lowest idx).
__device__ __forceinline__ unsigned long long pack_key(double v, int idx) {
    double c = fmax(v, 0.0);
    return (((unsigned long long)__double_as_longlong(c)) & KMASK)
         | (unsigned long long)((unsigned)idx & 0x1FFFu);
}
__device__ __forceinline__ double key_val(unsigned long long k) {
    return __longlong_as_double((long long)(k & KMASK));
}

// merge two (top2 + bound) chains with exact lowest-index tie-break.
__device__ __forceinline__ void merge2(
    float a0, float a1, int ai0, int ai1, float am,
    float b0, float b1, int bi0, int bi1, float bm,
    float& o0, float& o1, int& oi0, int& oi1, float& om) {
    float s3;
    const bool bWins = (b0 < a0) || (b0 == a0 && bi0 < ai0);
    if (!bWins) {
        o0 = a0; oi0 = ai0;
        const bool a1W = (a1 < b0) || (a1 == b0 && ai1 < bi0);
        if (a1W) { o1 = a1; oi1 = ai1; s3 = b0; }
        else     { o1 = b0; oi1 = bi0; s3 = fminf(a1, b1); }
    } else {
        o0 = b0; oi0 = bi0;
        const bool b1W = (b1 < a0) || (b1 == a0 && bi1 < ai0);
        if (b1W) { o1 = b1; oi1 = bi1; s3 = a0; }
        else     { o1 = a0; oi1 = ai0; s3 = fminf(b1, a1); }
    }
    om = fminf(fminf(am, bm), s3);
}

// 1024 threads = 16 row-waves per block; 256 blocks = one pass (R16-proven).
__global__ __launch_bounds__(1024) void cand_kernel(
    const float* __restrict__ logits,
    const float* __restrict__ pred_points,
    const float* __restrict__ tgt_points,
    float* __restrict__ cls_out,
    float* __restrict__ u0, int* __restrict__ jm, float* __restrict__ bnd,
    float* __restrict__ ccost, unsigned short* __restrict__ cidx) {
    extern __shared__ char sm[];
    float2* pd = (float2*)sm;            // 8192 float2 = 64KB
    float*  cl = (float*)(pd + NQ);      // 8192 float  = 32KB

    const int tid = threadIdx.x;
    const int b   = blockIdx.x >> 5;     // 32 blocks per batch

    const float4* p4 = (const float4*)(pred_points + (size_t)b * NQ * 2);
    for (int t = tid; t < NQ / 2; t += 1024) ((float4*)pd)[t] = p4[t];
    for (int t = tid; t < NQ; t += 1024) cl[t] = cls_f32(logits[b * NQ + t]);
    __syncthreads();
    if ((blockIdx.x & 31) == 0) {        // one block per batch exports cls
        for (int t = tid; t < NQ; t += 1024) cls_out[b * NQ + t] = cl[t];
    }

    const int w = tid >> 6, lane = tid & 63;
    const int i = (blockIdx.x & 31) * 16 + w;    // row in batch
    const int g = b * NT + i;                    // 0..4095
    const float tx = tgt_points[g * 2 + 0];
    const float ty = tgt_points[g * 2 + 1];

    float A0 = DINF, A1 = DINF, Am = DINF; int Ai0 = 0, Ai1 = 0;
    float B0 = DINF, B1 = DINF, Bm = DINF; int Bi0 = 0, Bi1 = 0;
    float C0 = DINF, C1 = DINF, Cm = DINF; int Ci0 = 0, Ci1 = 0;
    float D0 = DINF, D1 = DINF, Dm = DINF; int Di0 = 0, Di1 = 0;
    for (int k = 0; k < NQ / 256; ++k) {     // 32 iters, 4 cols each
        const int c = k * 256 + 4 * lane;
        const float4 p01 = ((const float4*)pd)[(c >> 1) + 0];
        const float4 p23 = ((const float4*)pd)[(c >> 1) + 1];
        const float4 c4  = ((const float4*)cl)[c >> 2];
        const float v0 = cost_f32(p01.x, p01.y, c4.x, tx, ty);
        const float v1 = cost_f32(p01.z, p01.w, c4.y, tx, ty);
        const float v2 = cost_f32(p23.x, p23.y, c4.z, tx, ty);
        const float v3 = cost_f32(p23.z, p23.w, c4.w, tx, ty);
        if (v0 < A1) { Am = A1; if (v0 < A0) { A1 = A0; Ai1 = Ai0; A0 = v0; Ai0 = c; } else { A1 = v0; Ai1 = c; } }
        else Am = fminf(Am, v0);
        if (v1 < B1) { Bm = B1; if (v1 < B0) { B1 = B0; Bi1 = Bi0; B0 = v1; Bi0 = c + 1; } else { B1 = v1; Bi1 = c + 1; } }
        else Bm = fminf(Bm, v1);
        if (v2 < C1) { Cm = C1; if (v2 < C0) { C1 = C0; Ci1 = Ci0; C0 = v2; Ci0 = c + 2; } else { C1 = v2; Ci1 = c + 2; } }
        else Cm = fminf(Cm, v2);
        if (v3 < D1) { Dm = D1; if (v3 < D0) { D1 = D0; Di1 = Di0; D0 = v3; Di0 = c + 3; } else { D1 = v3; Di1 = c + 3; } }
        else Dm = fminf(Dm, v3);
    }
    float ab0, ab1, abm; int abi0, abi1;
    float cd0, cd1, cdm; int cdi0, cdi1;
    float t0v, t1v, bb0; int t0i, t1i;
    merge2(A0, A1, Ai0, Ai1, Am, B0, B1, Bi0, Bi1, Bm, ab0, ab1, abi0, abi1, abm);
    merge2(C0, C1, Ci0, Ci1, Cm, D0, D1, Di0, Di1, Dm, cd0, cd1, cdi0, cdi1, cdm);
    merge2(ab0, ab1, abi0, abi1, abm, cd0, cd1, cdi0, cdi1, cdm, t0v, t1v, t0i, t1i, bb0);

    ((float2*)(ccost + ((size_t)g << 7)))[lane] = make_float2(t0v, t1v);
    ((ushort2*)(cidx + ((size_t)g << 7)))[lane] =
        make_ushort2((unsigned short)t0i, (unsigned short)t1i);
    float bv = t0v; int bc = t0i; float bb = bb0;
    for (int off = 32; off > 0; off >>= 1) {
        float ov = __shfl_down(bv, off, 64);
        int   oc = __shfl_down(bc, off, 64);
        float ob = __shfl_down(bb, off, 64);
        if (ov < bv || (ov == bv && oc < bc)) { bv = ov; bc = oc; }
        bb = fminf(bb, ob);
    }
    if (lane == 0) { u0[g] = bv; jm[g] = bc; bnd[g] = bb; }
}

// Fused: blocks [0,BS) = exact LSA (atomicMin greedy -> Jacobi sweep auction
// -> 1-barrier register-v SAP); blocks [BS,BS+CFB) = persistent C fill.
__global__ __launch_bounds__(NTHR, 1) void fused_kernel(
    const float* __restrict__ pred_points,
    const float* __restrict__ tgt_points,
    const float* __restrict__ cls,
    const float* __restrict__ u0,
    const int* __restrict__ jm,
    const float* __restrict__ bnd,
    const float* __restrict__ ccost,
    const unsigned short* __restrict__ cidx,
    float* __restrict__ C,
    float* __restrict__ out_rows,
    float* __restrict__ out_cols) {
    const int tid = threadIdx.x;

    // ---------------- persistent C-fill branch ----------------
    if (blockIdx.x >= BS) {
        const int cfid = blockIdx.x - BS;            // 0..CFB-1
        const int ngrp = BS * NQ / 16;               // 4096 groups of 16 queries
        const int g32  = tid & 31;
        for (int grp = cfid; grp < ngrp; grp += CFB) {
            const int bq = (grp << 4) + (tid >> 5);  // 16 queries per group
            const int b  = bq >> 13;
            const float2 q = ((const float2*)pred_points)[bq];
            const float clv = cls[bq];
            const float* tb = tgt_points + b * NT * 2;
#pragma unroll
            for (int s = 0; s < 4; ++s) {
                const int t = g32 * 4 + s * 128;
                float4 A  = *(const float4*)(tb + t * 2);
                float4 Bv = *(const float4*)(tb + t * 2 + 4);
                vf4 r;
                r.x = cost_f32(q.x, q.y, clv, A.x,  A.y);
                r.y = cost_f32(q.x, q.y, clv, A.z,  A.w);
                r.z = cost_f32(q.x, q.y, clv, Bv.x, Bv.y);
                r.w = cost_f32(q.x, q.y, clv, Bv.z, Bv.w);
                __builtin_nontemporal_store(r, (vf4*)(C + (size_t)bq * NT + t));
            }
        }
        return;
    }

    // ---------------- LSA branch ----------------
    const int b = blockIdx.x;
    extern __shared__ char smem[];
    double* v_s       = (double*)smem;                       // NQ
    double* u_s       = v_s + NQ;                            // NT
    double* l_minv    = u_s + NT;                            // MAXL
    double* l_v       = l_minv + MAXL;                       // MAXL
    double* gb_m2     = l_v + MAXL;                          // 64
    unsigned long long* gb_key = (unsigned long long*)(gb_m2 + 64);  // 64
    unsigned long long* p_k = gb_key + 64;                   // 2*NW
    float*  tg        = (float*)(p_k + 2 * NW);              // NT*2
    float*  bnd_s     = tg + NT * 2;                         // NT
    float*  gb_c      = bnd_s + NT;                          // 64
    int*    gb_j      = (int*)(gb_c + 64);                   // 64
    int*    wcnt      = gb_j + 64;                           // NW
    short*  path_s    = (short*)(wcnt + NW);                 // NQ
    short*  row4col_s = path_s + NQ;                         // NQ
    short*  col4row_s = row4col_s + NQ;                      // NT
    short*  jm_s      = col4row_s + NT;                      // NT
    short*  sap_s     = jm_s + NT;                           // NT
    short*  act_s     = sap_s + NT;                          // NT
    short*  l_k       = act_s + NT;                          // MAXL
    short*  l_r       = l_k + MAXL;                          // MAXL

    // init (v_s deferred: its space doubles as greedy scratch)
    for (int c = tid; c < NQ; c += NTHR) row4col_s[c] = -1;
    for (int r = tid; r < NT; r += NTHR) {
        col4row_s[r] = -1;
        u_s[r]   = (double)u0[b * NT + r];
        jm_s[r]  = (short)jm[b * NT + r];
        bnd_s[r] = bnd[b * NT + r];
    }
    for (int t = tid; t < NT * 2; t += NTHR) tg[t] = tgt_points[b * NT * 2 + t];

    // per-thread column state for SAP (registers)
    float  qx[CHUNKS], qy[CHUNKS], cl[CHUNKS];
    double vv[CHUNKS], sh[CHUNKS];
#pragma unroll
    for (int j = 0; j < CHUNKS; ++j) {
        int c = j * NTHR + tid;
        qx[j] = pred_points[(b * NQ + c) * 2 + 0];
        qy[j] = pred_points[(b * NQ + c) * 2 + 1];
        cl[j] = cls[b * NQ + c];
    }
    __syncthreads();

    // ---- greedy via LDS atomicMin (winner = lowest row); losers stay -1.
    {
        int* scratch = (int*)v_s;          // v_s not yet initialized
        const int r = tid;                 // NT == NTHR
        const int jmr = jm_s[r];
        scratch[jmr] = 0x7FFFFFFF;         // same-addr same-val: benign
        __syncthreads();
        atomicMin(&scratch[jmr], r);
        __syncthreads();
        if (scratch[jmr] == r) { col4row_s[r] = (short)jmr; row4col_s[jmr] = (short)r; }
        __syncthreads();
        for (int c = tid; c < NQ; c += NTHR) v_s[c] = 0.0;   // overwrites scratch
        __syncthreads();
    }

    // ---- Jacobi sweep auction: ALL unassigned rows bid simultaneously
    // (64 groups x 8 lanes, 16 candidates/lane). Per column, winner = max
    // key (m2-c | row) via redundant read-only scan of gb slots; winners
    // commit in parallel to DISJOINT addresses. Exact (R8 argument): bids
    // use sweep-start v; u=m2, v[j]=min(v, c-m2); other rows' slacks only
    // grow as v falls. Cert-fail -> flag -2 -> SAP. 4 barriers/sweep.
    {
        const int grp = tid >> 3, gl = tid & 7;    // 64 groups of 8 lanes
        int sweeps = 0;
        for (;;) {
            // step1: count + compact active rows (col4row == -1)
            const int r = tid;
            const bool act = (col4row_s[r] == (short)-1);
            const unsigned long long bal = __ballot(act);
            if ((tid & 63) == 0) wcnt[tid >> 6] = __popcll(bal);
            __syncthreads();                               // B_a
            int pre = 0, nact = 0;
            for (int x = 0; x < NW; ++x) {
                if (x < (tid >> 6)) pre += wcnt[x];
                nact += wcnt[x];
            }
            if (nact == 0 || sweeps >= SWCAP) break;       // uniform exit
            const int rank = pre + __popcll(bal & ((1ull << (tid & 63)) - 1ull));
            if (act) act_s[rank] = (short)r;
            __syncthreads();                               // B_b (act_s visible)

            const int ngr = (nact < 64) ? nact : 64;
            if (grp < ngr) {
                const int row = act_s[grp];
                const int g = (b << 9) + row;
                const float4*  cbase = (const float4*)(ccost + ((size_t)g << 7));
                const ushort4* ibase = (const ushort4*)(cidx + ((size_t)g << 7));
                float4 cf[4]; ushort4 ciq[4];
#pragma unroll
                for (int x = 0; x < 4; ++x) { cf[x] = cbase[gl * 4 + x]; ciq[x] = ibase[gl * 4 + x]; }
                unsigned long long k1 = ~0ull, k2m = ~0ull;   // k2m: value bits only
#pragma unroll
                for (int x = 0; x < 4; ++x) {
                    const float vc[4] = {cf[x].x, cf[x].y, cf[x].z, cf[x].w};
                    const unsigned short ic[4] = {ciq[x].x, ciq[x].y, ciq[x].z, ciq[x].w};
#pragma unroll
                    for (int y = 0; y < 4; ++y) {
                        const unsigned long long q = pack_key((double)vc[y] - v_s[ic[y]], ic[y]);
                        if (q < k1) { k2m = k1 & KMASK; k1 = q; }
                        else { const unsigned long long qm = q & KMASK; if (qm < k2m) k2m = qm; }
                    }
                }
                for (int m = 4; m > 0; m >>= 1) {          // 8-lane reduce
                    unsigned long long ok1 = __shfl_xor(k1, m, 8);
                    unsigned long long om2 = __shfl_xor(k2m, m, 8);
                    unsigned long long lo  = (ok1 < k1) ? ok1 : k1;
                    unsigned long long hiv = ((ok1 < k1) ? k1 : ok1) & KMASK;
                    k1 = lo;
                    if (om2 < k2m) k2m = om2;
                    if (hiv < k2m) k2m = hiv;
                }
                const int    j1  = (int)(k1 & 0x1FFFull);
                const double m2d = key_val(k2m);
                if (m2d < (double)bnd_s[row]) {
                    float csel = 0.0f;                     // c(row, j1): cost > 0 always
#pragma unroll
                    for (int x = 0; x < 4; ++x) {
                        if (ciq[x].x == (unsigned short)j1) csel = cf[x].x;
                        if (ciq[x].y == (unsigned short)j1) csel = cf[x].y;
                        if (ciq[x].z == (unsigned short)j1) csel = cf[x].z;
                        if (ciq[x].w == (unsigned short)j1) csel = cf[x].w;
                    }
                    for (int m = 4; m > 0; m >>= 1) csel = fmaxf(csel, __shfl_xor(csel, m, 8));
                    if (gl == 0) {
                        gb_key[grp] = pack_key(m2d - (double)csel, row);  // m2-c >= 0
                        gb_j[grp]   = j1;
                        gb_m2[grp]  = m2d;
                        gb_c[grp]   = csel;
                    }
                } else {
                    if (gl == 0) { gb_j[grp] = -1; col4row_s[row] = -2; }  // -> SAP
                }
            }
            __syncthreads();                               // B_c (gb_* visible)

            // resolve: per contested column, winner = max key; commit disjoint
            if (grp < ngr && gb_j[grp] >= 0) {
                const int row = act_s[grp];
                const int j1  = gb_j[grp];
                unsigned long long kb = gb_key[grp];
                int win = grp;
                for (int x = 0; x < ngr; ++x) {
                    if (gb_j[x] == j1) {
                        const unsigned long long kx = gb_key[x];
                        if (kx > kb) { kb = kx; win = x; }  // keys unique (row bits)
                    }
                }
                if (win == grp && gl == 0) {
                    const int rk = row4col_s[j1];          // own column: safe RMW
                    row4col_s[j1]  = (short)row;
                    col4row_s[row] = (short)j1;
                    u_s[row] = gb_m2[grp];
                    const double nv = (double)gb_c[grp] - gb_m2[grp];
                    if (nv < v_s[j1]) v_s[j1] = nv;        // only winner touches j1
                    if (rk >= 0) col4row_s[rk] = -1;       // kick previous owner
                }
            }
            __syncthreads();                               // B_d
            ++sweeps;
        }
    }
    __syncthreads();

    // ---- compact leftovers (active -1 or cert-fail -2) into SAP list
    int nsap;
    {
        const int r = tid;
        const bool un = (col4row_s[r] < 0);
        const unsigned long long bal = __ballot(un);
        if ((tid & 63) == 0) wcnt[tid >> 6] = __popcll(bal);
        __syncthreads();
        int pre = 0, tot = 0;
        for (int x = 0; x < NW; ++x) {
            if (x < (tid >> 6)) pre += wcnt[x];
            tot += wcnt[x];
        }
        const int rank = pre + __popcll(bal & ((1ull << (tid & 63)) - 1ull));
        if (un) { sap_s[rank] = (short)r; col4row_s[r] = -1; }
        nsap = tot;
        __syncthreads();
    }

    // refresh per-thread register v from LDS
#pragma unroll
    for (int j = 0; j < CHUNKS; ++j) vv[j] = v_s[j * NTHR + tid];

    // ---- SAP for leftovers: exact full scan, v in REGISTERS, 1 barrier/iter
    const int NL = nsap;
    for (int di = 0; di < NL; ++di) {
        const int cur_row = sap_s[di];
#pragma unroll
        for (int j = 0; j < CHUNKS; ++j) sh[j] = DINF;
        int    i    = cur_row;
        double minv = 0.0;
        int    len  = 0;
        int    sink = -1;

        for (;;) {
            const double w  = minv - u_s[i];
            const float  tx = tg[i * 2 + 0];
            const float  ty = tg[i * 2 + 1];

            double best = DINF;
            int bestc = NQ;
#pragma unroll
            for (int j = 0; j < CHUNKS; ++j) {
                const int c = j * NTHR + tid;
                float  cf = cost_f32(qx[j], qy[j], cl[j], tx, ty);
                double rr = (w + (double)cf) - vv[j];
                if (rr < sh[j]) { sh[j] = rr; path_s[c] = (short)i; }
                if (sh[j] < best) { best = sh[j]; bestc = c; }
            }
            unsigned long long bkey = pack_key(best, bestc);
            for (int off = 32; off > 0; off >>= 1) {
                unsigned long long ok = __shfl_down(bkey, off, 64);
                if (ok < bkey) bkey = ok;
            }
            const int par = len & 1;
            if ((tid & 63) == 0) p_k[par * NW + (tid >> 6)] = bkey;
            __syncthreads();                   // the ONE barrier per iteration
            bkey = p_k[par * NW + (tid & (NW - 1))];
            for (int m = NW >> 1; m > 0; m >>= 1) {
                unsigned long long ok = __shfl_xor(bkey, m, 64);
                if (ok < bkey) bkey = ok;
            }
            minv = key_val(bkey);
            const int k  = (int)(bkey & 0x1FFFull);
            const int rk = row4col_s[k];       // stable during Dijkstra
            if ((k & (NTHR - 1)) == tid) {     // owner: save+neutralize column
                const int jj = k >> 9;
#pragma unroll
                for (int j = 0; j < CHUNKS; ++j)
                    if (j == jj) { l_v[len] = vv[j]; vv[j] = -DINF; sh[j] = DINF; }
            }
            if (tid == 0) { l_k[len] = (short)k; l_minv[len] = minv; l_r[len] = (short)rk; }
            ++len;
            if (rk < 0) { sink = k; break; }
            i = rk;
        }
        __syncthreads();   // l_* / path_s writes visible

        const int L = len;
        for (int e = tid; e < L; e += NTHR) {
            const int rk2 = l_r[e];
            if (rk2 >= 0) u_s[rk2] += minv - l_minv[e];
        }
        if (tid == 0) u_s[cur_row] += minv;
        for (int e = 0; e < L; ++e) {          // owner restores its register v
            const int k2 = l_k[e];
            if ((k2 & (NTHR - 1)) == tid) {
                const int jj = k2 >> 9;
                const double nv = l_v[e] - (minv - l_minv[e]);
#pragma unroll
                for (int j = 0; j < CHUNKS; ++j)
                    if (j == jj) vv[j] = nv;
            }
        }
        if (tid == 0) {   // augment along the alternating path
            int j = sink;
            for (;;) {
                const int ii = path_s[j];
                row4col_s[j] = (short)ii;
                const int t = col4row_s[ii];
                col4row_s[ii] = (short)j;
                j = t;
                if (ii == cur_row) break;
            }
        }
        __syncthreads();
    }

    // row_ind = sorted(col4row), col_ind = argsort(col4row); values distinct
    for (int r = tid; r < NT; r += NTHR) {
        const int q = col4row_s[r];
        int rank = 0;
        for (int r2 = 0; r2 < NT; ++r2) rank += (col4row_s[r2] < q) ? 1 : 0;
        out_rows[b * NT + rank] = (float)q;
        out_cols[b * NT + rank] = (float)r;
    }
}

extern "C" void kernel_launch(void* const* d_in, const int* in_sizes, int n_in,
                              void* d_out, int out_size, void* d_ws, size_t ws_size,
                              hipStream_t stream) {
    const float* logits = (const float*)d_in[0];  // (8, 8192, 1)
    const float* pred   = (const float*)d_in[1];  // (8, 8192, 2)
    const float* tgt    = (const float*)d_in[2];  // (8, 512, 2)

    float* out  = (float*)d_out;
    float* C    = out;                                   // BS*NQ*NT
    float* orow = out + (size_t)BS * NQ * NT;            // BS*NT
    float* ocol = orow + (size_t)BS * NT;                // BS*NT

    char*  ws    = (char*)d_ws;
    float* cls   = (float*)ws;                                  // 256 KB
    float* u0    = (float*)(ws + 262144);                       // 16 KB
    float* bndp  = (float*)(ws + 278528);                       // 16 KB
    int*   jmn   = (int*)(ws + 294912);                         // 16 KB
    float* ccost = (float*)(ws + 311296);                       // 2 MB
    unsigned short* cidx = (unsigned short*)(ws + 311296 + 2097152); // 1 MB

    const size_t smem_cand  = 98304;    // 96 KB: pred(64K) + cls(32K)
    const size_t smem_fused = 126976;   // ~124 KB (see LDS layout)

    cand_kernel<<<BS * 32, 1024, smem_cand, stream>>>(
        logits, pred, tgt, cls, u0, jmn, bndp, ccost, cidx);
    fused_kernel<<<BS + CFB, NTHR, smem_fused, stream>>>(
        pred, tgt, cls, u0, jmn, bndp, ccost, cidx, C, orow, ocol);
}

// Round 19
// 71.587 us; speedup vs baseline: 2.7471x; 1.0197x over previous
//
#include <hip/hip_runtime.h>
#include <math.h>

#define BS 8
#define NQ 8192
#define NT 512
#define NTHR 512
#define CHUNKS 16            // NQ / NTHR columns per thread (SAP scan)
#define NW (NTHR / 64)       // 8 waves
#define MAXL (NT + 2)
#define KMASK 0xFFFFFFFFFFFFE000ull
#define CFB 240              // persistent C-fill blocks
#define SWCAP 32             // Jacobi sweep cap (SAP finishes leftovers)
#define STAGN 4              // break after this many non-decreasing-nact sweeps

#define DINF (__builtin_inf())

typedef float vf4 __attribute__((ext_vector_type(4)));

// f32 cost, FMA-contraction-free, bit-identical everywhere it is computed.
__device__ __forceinline__ float cost_f32(float qx, float qy, float cl, float tx, float ty) {
    float dx = __fsub_rn(qx, tx);
    float dy = __fsub_rn(qy, ty);
    float d2 = __fadd_rn(__fmul_rn(dx, dx), __fmul_rn(dy, dy));
    float d  = __fsqrt_rn(d2);
    return __fadd_rn(__fmul_rn(0.5f, d), cl);
}

__device__ __forceinline__ float cls_f32(float x) {
    float s;
    if (x >= 0.0f) { float e = expf(-x); s = 1.0f / (1.0f + e); }
    else           { float e = expf(x);  s = e / (1.0f + e); }
    return __fsub_rn(1.0f, s);
}

// packed (value,idx) key: non-negative doubles compare as u64 bits;
// low 13 bits hold idx -> min == (min value, lowest idx).
__device__ __forceinline__ unsigned long long pack_key(double v, int idx) {
    double c = fmax(v, 0.0);
    return (((unsigned long long)__double_as_longlong(c)) & KMASK)
         | (unsigned long long)((unsigned)idx & 0x1FFFu);
}
__device__ __forceinline__ double key_val(unsigned long long k) {
    return __longlong_as_double((long long)(k & KMASK));
}

// merge two (top2 + bound) chains with exact lowest-index tie-break.
__device__ __forceinline__ void merge2(
    float a0, float a1, int ai0, int ai1, float am,
    float b0, float b1, int bi0, int bi1, float bm,
    float& o0, float& o1, int& oi0, int& oi1, float& om) {
    float s3;
    const bool bWins = (b0 < a0) || (b0 == a0 && bi0 < ai0);
    if (!bWins) {
        o0 = a0; oi0 = ai0;
        const bool a1W = (a1 < b0) || (a1 == b0 && ai1 < bi0);
        if (a1W) { o1 = a1; oi1 = ai1; s3 = b0; }
        else     { o1 = b0; oi1 = bi0; s3 = fminf(a1, b1); }
    } else {
        o0 = b0; oi0 = bi0;
        const bool b1W = (b1 < a0) || (b1 == a0 && bi1 < ai0);
        if (b1W) { o1 = b1; oi1 = bi1; s3 = a0; }
        else     { o1 = a0; oi1 = ai0; s3 = fminf(b1, a1); }
    }
    om = fminf(fminf(am, bm), s3);
}

// 1024 threads = 16 row-waves per block; 256 blocks = one pass (R16-proven).
__global__ __launch_bounds__(1024) void cand_kernel(
    const float* __restrict__ logits,
    const float* __restrict__ pred_points,
    const float* __restrict__ tgt_points,
    float* __restrict__ cls_out,
    float* __restrict__ u0, int* __restrict__ jm, float* __restrict__ bnd,
    float* __restrict__ ccost, unsigned short* __restrict__ cidx) {
    extern __shared__ char sm[];
    float2* pd = (float2*)sm;            // 8192 float2 = 64KB
    float*  cl = (float*)(pd + NQ);      // 8192 float  = 32KB

    const int tid = threadIdx.x;
    const int b   = blockIdx.x >> 5;     // 32 blocks per batch

    const float4* p4 = (const float4*)(pred_points + (size_t)b * NQ * 2);
    for (int t = tid; t < NQ / 2; t += 1024) ((float4*)pd)[t] = p4[t];
    for (int t = tid; t < NQ; t += 1024) cl[t] = cls_f32(logits[b * NQ + t]);
    __syncthreads();
    if ((blockIdx.x & 31) == 0) {        // one block per batch exports cls
        for (int t = tid; t < NQ; t += 1024) cls_out[b * NQ + t] = cl[t];
    }

    const int w = tid >> 6, lane = tid & 63;
    const int i = (blockIdx.x & 31) * 16 + w;    // row in batch
    const int g = b * NT + i;                    // 0..4095
    const float tx = tgt_points[g * 2 + 0];
    const float ty = tgt_points[g * 2 + 1];

    float A0 = DINF, A1 = DINF, Am = DINF; int Ai0 = 0, Ai1 = 0;
    float B0 = DINF, B1 = DINF, Bm = DINF; int Bi0 = 0, Bi1 = 0;
    float C0 = DINF, C1 = DINF, Cm = DINF; int Ci0 = 0, Ci1 = 0;
    float D0 = DINF, D1 = DINF, Dm = DINF; int Di0 = 0, Di1 = 0;
    for (int k = 0; k < NQ / 256; ++k) {     // 32 iters, 4 cols each
        const int c = k * 256 + 4 * lane;
        const float4 p01 = ((const float4*)pd)[(c >> 1) + 0];
        const float4 p23 = ((const float4*)pd)[(c >> 1) + 1];
        const float4 c4  = ((const float4*)cl)[c >> 2];
        const float v0 = cost_f32(p01.x, p01.y, c4.x, tx, ty);
        const float v1 = cost_f32(p01.z, p01.w, c4.y, tx, ty);
        const float v2 = cost_f32(p23.x, p23.y, c4.z, tx, ty);
        const float v3 = cost_f32(p23.z, p23.w, c4.w, tx, ty);
        if (v0 < A1) { Am = A1; if (v0 < A0) { A1 = A0; Ai1 = Ai0; A0 = v0; Ai0 = c; } else { A1 = v0; Ai1 = c; } }
        else Am = fminf(Am, v0);
        if (v1 < B1) { Bm = B1; if (v1 < B0) { B1 = B0; Bi1 = Bi0; B0 = v1; Bi0 = c + 1; } else { B1 = v1; Bi1 = c + 1; } }
        else Bm = fminf(Bm, v1);
        if (v2 < C1) { Cm = C1; if (v2 < C0) { C1 = C0; Ci1 = Ci0; C0 = v2; Ci0 = c + 2; } else { C1 = v2; Ci1 = c + 2; } }
        else Cm = fminf(Cm, v2);
        if (v3 < D1) { Dm = D1; if (v3 < D0) { D1 = D0; Di1 = Di0; D0 = v3; Di0 = c + 3; } else { D1 = v3; Di1 = c + 3; } }
        else Dm = fminf(Dm, v3);
    }
    float ab0, ab1, abm; int abi0, abi1;
    float cd0, cd1, cdm; int cdi0, cdi1;
    float t0v, t1v, bb0; int t0i, t1i;
    merge2(A0, A1, Ai0, Ai1, Am, B0, B1, Bi0, Bi1, Bm, ab0, ab1, abi0, abi1, abm);
    merge2(C0, C1, Ci0, Ci1, Cm, D0, D1, Di0, Di1, Dm, cd0, cd1, cdi0, cdi1, cdm);
    merge2(ab0, ab1, abi0, abi1, abm, cd0, cd1, cdi0, cdi1, cdm, t0v, t1v, t0i, t1i, bb0);

    ((float2*)(ccost + ((size_t)g << 7)))[lane] = make_float2(t0v, t1v);
    ((ushort2*)(cidx + ((size_t)g << 7)))[lane] =
        make_ushort2((unsigned short)t0i, (unsigned short)t1i);
    float bv = t0v; int bc = t0i; float bb = bb0;
    for (int off = 32; off > 0; off >>= 1) {
        float ov = __shfl_down(bv, off, 64);
        int   oc = __shfl_down(bc, off, 64);
        float ob = __shfl_down(bb, off, 64);
        if (ov < bv || (ov == bv && oc < bc)) { bv = ov; bc = oc; }
        bb = fminf(bb, ob);
    }
    if (lane == 0) { u0[g] = bv; jm[g] = bc; bnd[g] = bb; }
}

// Fused: blocks [0,BS) = exact LSA (atomicMin greedy -> Jacobi sweep auction
// with stagnation break -> 1-barrier register-v SAP); blocks [BS,BS+CFB) =
// persistent grid-stride nontemporal C fill.
__global__ __launch_bounds__(NTHR, 1) void fused_kernel(
    const float* __restrict__ pred_points,
    const float* __restrict__ tgt_points,
    const float* __restrict__ cls,
    const float* __restrict__ u0,
    const int* __restrict__ jm,
    const float* __restrict__ bnd,
    const float* __restrict__ ccost,
    const unsigned short* __restrict__ cidx,
    float* __restrict__ C,
    float* __restrict__ out_rows,
    float* __restrict__ out_cols) {
    const int tid = threadIdx.x;

    // ---------------- persistent C-fill branch ----------------
    if (blockIdx.x >= BS) {
        const int cfid = blockIdx.x - BS;            // 0..CFB-1
        const int ngrp = BS * NQ / 16;               // 4096 groups of 16 queries
        const int g32  = tid & 31;
        for (int grp = cfid; grp < ngrp; grp += CFB) {
            const int bq = (grp << 4) + (tid >> 5);  // 16 queries per group
            const int b  = bq >> 13;
            const float2 q = ((const float2*)pred_points)[bq];
            const float clv = cls[bq];
            const float* tb = tgt_points + b * NT * 2;
#pragma unroll
            for (int s = 0; s < 4; ++s) {
                const int t = g32 * 4 + s * 128;
                float4 A  = *(const float4*)(tb + t * 2);
                float4 Bv = *(const float4*)(tb + t * 2 + 4);
                vf4 r;
                r.x = cost_f32(q.x, q.y, clv, A.x,  A.y);
                r.y = cost_f32(q.x, q.y, clv, A.z,  A.w);
                r.z = cost_f32(q.x, q.y, clv, Bv.x, Bv.y);
                r.w = cost_f32(q.x, q.y, clv, Bv.z, Bv.w);
                __builtin_nontemporal_store(r, (vf4*)(C + (size_t)bq * NT + t));
            }
        }
        return;
    }

    // ---------------- LSA branch ----------------
    const int b = blockIdx.x;
    extern __shared__ char smem[];
    double* v_s       = (double*)smem;                       // NQ
    double* u_s       = v_s + NQ;                            // NT
    double* l_minv    = u_s + NT;                            // MAXL
    double* l_v       = l_minv + MAXL;                       // MAXL
    double* gb_m2     = l_v + MAXL;                          // 64
    unsigned long long* gb_key = (unsigned long long*)(gb_m2 + 64);  // 64
    unsigned long long* p_k = gb_key + 64;                   // 2*NW
    float*  tg        = (float*)(p_k + 2 * NW);              // NT*2
    float*  bnd_s     = tg + NT * 2;                         // NT
    float*  gb_c      = bnd_s + NT;                          // 64
    int*    gb_j      = (int*)(gb_c + 64);                   // 64
    int*    wcnt      = gb_j + 64;                           // NW
    short*  path_s    = (short*)(wcnt + NW);                 // NQ
    short*  row4col_s = path_s + NQ;                         // NQ
    short*  col4row_s = row4col_s + NQ;                      // NT
    short*  jm_s      = col4row_s + NT;                      // NT
    short*  sap_s     = jm_s + NT;                           // NT
    short*  act_s     = sap_s + NT;                          // NT
    short*  l_k       = act_s + NT;                          // MAXL
    short*  l_r       = l_k + MAXL;                          // MAXL

    // init (v_s deferred: its space doubles as greedy scratch)
    for (int c = tid; c < NQ; c += NTHR) row4col_s[c] = -1;
    for (int r = tid; r < NT; r += NTHR) {
        col4row_s[r] = -1;
        u_s[r]   = (double)u0[b * NT + r];
        jm_s[r]  = (short)jm[b * NT + r];
        bnd_s[r] = bnd[b * NT + r];
    }
    for (int t = tid; t < NT * 2; t += NTHR) tg[t] = tgt_points[b * NT * 2 + t];

    // per-thread column state for SAP (registers)
    float  qx[CHUNKS], qy[CHUNKS], cl[CHUNKS];
    double vv[CHUNKS], sh[CHUNKS];
#pragma unroll
    for (int j = 0; j < CHUNKS; ++j) {
        int c = j * NTHR + tid;
        qx[j] = pred_points[(b * NQ + c) * 2 + 0];
        qy[j] = pred_points[(b * NQ + c) * 2 + 1];
        cl[j] = cls[b * NQ + c];
    }
    __syncthreads();

    // ---- greedy via LDS atomicMin (winner = lowest row); losers stay -1.
    {
        int* scratch = (int*)v_s;          // v_s not yet initialized
        const int r = tid;                 // NT == NTHR
        const int jmr = jm_s[r];
        scratch[jmr] = 0x7FFFFFFF;         // same-addr same-val: benign
        __syncthreads();
        atomicMin(&scratch[jmr], r);
        __syncthreads();
        if (scratch[jmr] == r) { col4row_s[r] = (short)jmr; row4col_s[jmr] = (short)r; }
        __syncthreads();
        for (int c = tid; c < NQ; c += NTHR) v_s[c] = 0.0;   // overwrites scratch
        __syncthreads();
    }

    // ---- Jacobi sweep auction with stagnation break. All unassigned rows
    // bid simultaneously (64 groups x 8 lanes, 16 candidates/lane); per
    // column, winner = max key (m2-c | row); winners commit disjointly.
    // Exact (R8 argument). If nact fails to DECREASE for STAGN consecutive
    // sweeps (kick chains / near-tie ping-pong), bail to the exact SAP --
    // SAP resolves such rows at comparable or lower cost per row.
    {
        const int grp = tid >> 3, gl = tid & 7;    // 64 groups of 8 lanes
        int sweeps = 0, prev_nact = NT + 1, stagn = 0;
        for (;;) {
            // step1: count + compact active rows (col4row == -1)
            const int r = tid;
            const bool act = (col4row_s[r] == (short)-1);
            const unsigned long long bal = __ballot(act);
            if ((tid & 63) == 0) wcnt[tid >> 6] = __popcll(bal);
            __syncthreads();                               // B_a
            int pre = 0, nact = 0;
            for (int x = 0; x < NW; ++x) {
                if (x < (tid >> 6)) pre += wcnt[x];
                nact += wcnt[x];
            }
            if (nact == 0 || sweeps >= SWCAP) break;       // uniform exit
            stagn = (nact >= prev_nact) ? stagn + 1 : 0;
            if (stagn >= STAGN) break;                     // uniform: stalled
            prev_nact = nact;
            const int rank = pre + __popcll(bal & ((1ull << (tid & 63)) - 1ull));
            if (act) act_s[rank] = (short)r;
            __syncthreads();                               // B_b (act_s visible)

            const int ngr = (nact < 64) ? nact : 64;
            if (grp < ngr) {
                const int row = act_s[grp];
                const int g = (b << 9) + row;
                const float4*  cbase = (const float4*)(ccost + ((size_t)g << 7));
                const ushort4* ibase = (const ushort4*)(cidx + ((size_t)g << 7));
                float4 cf[4]; ushort4 ciq[4];
#pragma unroll
                for (int x = 0; x < 4; ++x) { cf[x] = cbase[gl * 4 + x]; ciq[x] = ibase[gl * 4 + x]; }
                unsigned long long k1 = ~0ull, k2m = ~0ull;   // k2m: value bits only
#pragma unroll
                for (int x = 0; x < 4; ++x) {
                    const float vc[4] = {cf[x].x, cf[x].y, cf[x].z, cf[x].w};
                    const unsigned short ic[4] = {ciq[x].x, ciq[x].y, ciq[x].z, ciq[x].w};
#pragma unroll
                    for (int y = 0; y < 4; ++y) {
                        const unsigned long long q = pack_key((double)vc[y] - v_s[ic[y]], ic[y]);
                        if (q < k1) { k2m = k1 & KMASK; k1 = q; }
                        else { const unsigned long long qm = q & KMASK; if (qm < k2m) k2m = qm; }
                    }
                }
                for (int m = 4; m > 0; m >>= 1) {          // 8-lane reduce
                    unsigned long long ok1 = __shfl_xor(k1, m, 8);
                    unsigned long long om2 = __shfl_xor(k2m, m, 8);
                    unsigned long long lo  = (ok1 < k1) ? ok1 : k1;
                    unsigned long long hiv = ((ok1 < k1) ? k1 : ok1) & KMASK;
                    k1 = lo;
                    if (om2 < k2m) k2m = om2;
                    if (hiv < k2m) k2m = hiv;
                }
                const int    j1  = (int)(k1 & 0x1FFFull);
                const double m2d = key_val(k2m);
                if (m2d < (double)bnd_s[row]) {
                    float csel = 0.0f;                     // c(row, j1): cost > 0 always
#pragma unroll
                    for (int x = 0; x < 4; ++x) {
                        if (ciq[x].x == (unsigned short)j1) csel = cf[x].x;
                        if (ciq[x].y == (unsigned short)j1) csel = cf[x].y;
                        if (ciq[x].z == (unsigned short)j1) csel = cf[x].z;
                        if (ciq[x].w == (unsigned short)j1) csel = cf[x].w;
                    }
                    for (int m = 4; m > 0; m >>= 1) csel = fmaxf(csel, __shfl_xor(csel, m, 8));
                    if (gl == 0) {
                        gb_key[grp] = pack_key(m2d - (double)csel, row);  // m2-c >= 0
                        gb_j[grp]   = j1;
                        gb_m2[grp]  = m2d;
                        gb_c[grp]   = csel;
                    }
                } else {
                    if (gl == 0) { gb_j[grp] = -1; col4row_s[row] = -2; }  // -> SAP
                }
            }
            __syncthreads();                               // B_c (gb_* visible)

            // resolve: per contested column, winner = max key; commit disjoint
            if (grp < ngr && gb_j[grp] >= 0) {
                const int row = act_s[grp];
                const int j1  = gb_j[grp];
                unsigned long long kb = gb_key[grp];
                int win = grp;
                for (int x = 0; x < ngr; ++x) {
                    if (gb_j[x] == j1) {
                        const unsigned long long kx = gb_key[x];
                        if (kx > kb) { kb = kx; win = x; }  // keys unique (row bits)
                    }
                }
                if (win == grp && gl == 0) {
                    const int rk = row4col_s[j1];          // own column: safe RMW
                    row4col_s[j1]  = (short)row;
                    col4row_s[row] = (short)j1;
                    u_s[row] = gb_m2[grp];
                    const double nv = (double)gb_c[grp] - gb_m2[grp];
                    if (nv < v_s[j1]) v_s[j1] = nv;        // only winner touches j1
                    if (rk >= 0) col4row_s[rk] = -1;       // kick previous owner
                }
            }
            __syncthreads();                               // B_d
            ++sweeps;
        }
    }
    __syncthreads();

    // ---- compact leftovers (active -1 or cert-fail -2) into SAP list
    int nsap;
    {
        const int r = tid;
        const bool un = (col4row_s[r] < 0);
        const unsigned long long bal = __ballot(un);
        if ((tid & 63) == 0) wcnt[tid >> 6] = __popcll(bal);
        __syncthreads();
        int pre = 0, tot = 0;
        for (int x = 0; x < NW; ++x) {
            if (x < (tid >> 6)) pre += wcnt[x];
            tot += wcnt[x];
        }
        const int rank = pre + __popcll(bal & ((1ull << (tid & 63)) - 1ull));
        if (un) { sap_s[rank] = (short)r; col4row_s[r] = -1; }
        nsap = tot;
        __syncthreads();
    }

    // refresh per-thread register v from LDS
#pragma unroll
    for (int j = 0; j < CHUNKS; ++j) vv[j] = v_s[j * NTHR + tid];

    // ---- SAP for leftovers: exact full scan, v in REGISTERS, 1 barrier/iter
    const int NL = nsap;
    for (int di = 0; di < NL; ++di) {
        const int cur_row = sap_s[di];
#pragma unroll
        for (int j = 0; j < CHUNKS; ++j) sh[j] = DINF;
        int    i    = cur_row;
        double minv = 0.0;
        int    len  = 0;
        int    sink = -1;

        for (;;) {
            const double w  = minv - u_s[i];
            const float  tx = tg[i * 2 + 0];
            const float  ty = tg[i * 2 + 1];

            double best = DINF;
            int bestc = NQ;
#pragma unroll
            for (int j = 0; j < CHUNKS; ++j) {
                const int c = j * NTHR + tid;
                float  cf = cost_f32(qx[j], qy[j], cl[j], tx, ty);
                double rr = (w + (double)cf) - vv[j];
                if (rr < sh[j]) { sh[j] = rr; path_s[c] = (short)i; }
                if (sh[j] < best) { best = sh[j]; bestc = c; }
            }
            unsigned long long bkey = pack_key(best, bestc);
            for (int off = 32; off > 0; off >>= 1) {
                unsigned long long ok = __shfl_down(bkey, off, 64);
                if (ok < bkey) bkey = ok;
            }
            const int par = len & 1;
            if ((tid & 63) == 0) p_k[par * NW + (tid >> 6)] = bkey;
            __syncthreads();                   // the ONE barrier per iteration
            bkey = p_k[par * NW + (tid & (NW - 1))];
            for (int m = NW >> 1; m > 0; m >>= 1) {
                unsigned long long ok = __shfl_xor(bkey, m, 64);
                if (ok < bkey) bkey = ok;
            }
            minv = key_val(bkey);
            const int k  = (int)(bkey & 0x1FFFull);
            const int rk = row4col_s[k];       // stable during Dijkstra
            if ((k & (NTHR - 1)) == tid) {     // owner: save+neutralize column
                const int jj = k >> 9;
#pragma unroll
                for (int j = 0; j < CHUNKS; ++j)
                    if (j == jj) { l_v[len] = vv[j]; vv[j] = -DINF; sh[j] = DINF; }
            }
            if (tid == 0) { l_k[len] = (short)k; l_minv[len] = minv; l_r[len] = (short)rk; }
            ++len;
            if (rk < 0) { sink = k; break; }
            i = rk;
        }
        __syncthreads();   // l_* / path_s writes visible

        const int L = len;
        for (int e = tid; e < L; e += NTHR) {
            const int rk2 = l_r[e];
            if (rk2 >= 0) u_s[rk2] += minv - l_minv[e];
        }
        if (tid == 0) u_s[cur_row] += minv;
        for (int e = 0; e < L; ++e) {          // owner restores its register v
            const int k2 = l_k[e];
            if ((k2 & (NTHR - 1)) == tid) {
                const int jj = k2 >> 9;
                const double nv = l_v[e] - (minv - l_minv[e]);
#pragma unroll
                for (int j = 0; j < CHUNKS; ++j)
                    if (j == jj) vv[j] = nv;
            }
        }
        if (tid == 0) {   // augment along the alternating path
            int j = sink;
            for (;;) {
                const int ii = path_s[j];
                row4col_s[j] = (short)ii;
                const int t = col4row_s[ii];
                col4row_s[ii] = (short)j;
                j = t;
                if (ii == cur_row) break;
            }
        }
        __syncthreads();
    }

    // row_ind = sorted(col4row), col_ind = argsort(col4row); values distinct
    for (int r = tid; r < NT; r += NTHR) {
        const int q = col4row_s[r];
        int rank = 0;
        for (int r2 = 0; r2 < NT; ++r2) rank += (col4row_s[r2] < q) ? 1 : 0;
        out_rows[b * NT + rank] = (float)q;
        out_cols[b * NT + rank] = (float)r;
    }
}

extern "C" void kernel_launch(void* const* d_in, const int* in_sizes, int n_in,
                              void* d_out, int out_size, void* d_ws, size_t ws_size,
                              hipStream_t stream) {
    const float* logits = (const float*)d_in[0];  // (8, 8192, 1)
    const float* pred   = (const float*)d_in[1];  // (8, 8192, 2)
    const float* tgt    = (const float*)d_in[2];  // (8, 512, 2)

    float* out  = (float*)d_out;
    float* C    = out;                                   // BS*NQ*NT
    float* orow = out + (size_t)BS * NQ * NT;            // BS*NT
    float* ocol = orow + (size_t)BS * NT;                // BS*NT

    char*  ws    = (char*)d_ws;
    float* cls   = (float*)ws;                                  // 256 KB
    float* u0    = (float*)(ws + 262144);                       // 16 KB
    float* bndp  = (float*)(ws + 278528);                       // 16 KB
    int*   jmn   = (int*)(ws + 294912);                         // 16 KB
    float* ccost = (float*)(ws + 311296);                       // 2 MB
    unsigned short* cidx = (unsigned short*)(ws + 311296 + 2097152); // 1 MB

    const size_t smem_cand  = 98304;    // 96 KB: pred(64K) + cls(32K)
    const size_t smem_fused = 126976;   // ~124 KB (see LDS layout)

    cand_kernel<<<BS * 32, 1024, smem_cand, stream>>>(
        logits, pred, tgt, cls, u0, jmn, bndp, ccost, cidx);
    fused_kernel<<<BS + CFB, NTHR, smem_fused, stream>>>(
        pred, tgt, cls, u0, jmn, bndp, ccost, cidx, C, orow, ocol);
}